// Round 1
// baseline (886.854 us; speedup 1.0000x reference)
//
#include <hip/hip_runtime.h>
#include <cstddef>

#define B_ 4
#define T_ 12
#define N_ 512
#define D_ 256
#define H_ 4
#define SEG_ 6
#define BT_ (B_*T_)

#define SCALE_S 0.35355339059327373f   /* 8^-0.5  */
#define SCALE_H 0.25f                  /* 16^-0.5 */
#define LAMBDA_INIT 0.2f
#define EPS_ 1e-6f

// ---------------------------------------------------------------------------
// Generic tiled GEMM:  O[m, ocol+e] = sum_k X[m,k] * W[e,k] (+ bias[e])
// X: [M][K] row-major contiguous, W: [E][K] row-major, O row stride = ldo.
// M, E, K all multiples of 64.
// ---------------------------------------------------------------------------
__global__ __launch_bounds__(256) void gemm_xt(
    const float* __restrict__ X, const float* __restrict__ W,
    const float* __restrict__ bias, float* __restrict__ O,
    int M, int E, int K, int ldo, int ocol)
{
    __shared__ float Xl[64][65];
    __shared__ float Wl[64][65];
    const int m0 = blockIdx.y * 64;
    const int e0 = blockIdx.x * 64;
    const int tid = threadIdx.x;
    const int cg = tid & 15;   // 16 col groups of 4
    const int rg = tid >> 4;   // 16 row groups of 4

    float acc[4][4] = {};

    for (int kk = 0; kk < K; kk += 64) {
        for (int i = tid; i < 64 * 64; i += 256) {
            int r = i >> 6, c = i & 63;
            Xl[r][c] = X[(size_t)(m0 + r) * K + kk + c];
            Wl[r][c] = W[(size_t)(e0 + r) * K + kk + c];
        }
        __syncthreads();
        for (int k = 0; k < 64; k++) {
            float xv[4], wv[4];
#pragma unroll
            for (int i = 0; i < 4; i++) { xv[i] = Xl[rg * 4 + i][k]; wv[i] = Wl[cg * 4 + i][k]; }
#pragma unroll
            for (int i = 0; i < 4; i++)
#pragma unroll
                for (int j = 0; j < 4; j++) acc[i][j] += xv[i] * wv[j];
        }
        __syncthreads();
    }

#pragma unroll
    for (int i = 0; i < 4; i++) {
        int row = m0 + rg * 4 + i;
        float* orow = O + (size_t)row * ldo + ocol + e0;
#pragma unroll
        for (int j = 0; j < 4; j++) {
            float v = acc[i][j];
            if (bias) v += bias[e0 + cg * 4 + j];
            orow[cg * 4 + j] = v;
        }
    }
}

// ---------------------------------------------------------------------------
// Spatial differential attention. One block per (bt, h). 512x512, dual softmax,
// online. K/V head-slices staged in LDS. Writes st channels [0,64).
// ---------------------------------------------------------------------------
__global__ __launch_bounds__(256) void spatial_diff_kernel(
    const float* __restrict__ q_s, const float* __restrict__ k_s, const float* __restrict__ v_s,
    const float* __restrict__ lq1, const float* __restrict__ lk1,
    const float* __restrict__ lq2, const float* __restrict__ lk2,
    const float* __restrict__ subln, float* __restrict__ st)
{
    const int h = blockIdx.x % H_;
    const int bt = blockIdx.x / H_;
    __shared__ float Kl[N_][16];
    __shared__ float Vl[N_][16];

    const float* kbase = k_s + (size_t)bt * N_ * 64 + h * 16;
    const float* vbase = v_s + (size_t)bt * N_ * 64 + h * 16;
    for (int i = threadIdx.x; i < N_ * 16; i += 256) {
        int m = i >> 4, j = i & 15;
        Kl[m][j] = kbase[(size_t)m * 64 + j];
        Vl[m][j] = vbase[(size_t)m * 64 + j];
    }
    __syncthreads();

    float e1 = 0.f, e2 = 0.f;
#pragma unroll
    for (int j = 0; j < 8; j++) { e1 += lq1[j] * lk1[j]; e2 += lq2[j] * lk2[j]; }
    const float lam = __expf(e1) - __expf(e2) + LAMBDA_INIT;

    for (int n = threadIdx.x; n < N_; n += 256) {
        float q[16];
        const float* qrow = q_s + ((size_t)bt * N_ + n) * 64 + h * 16;
#pragma unroll
        for (int j = 0; j < 16; j++) q[j] = qrow[j];

        float m1 = -1e30f, s1 = 0.f, m2 = -1e30f, s2 = 0.f;
        float o1[16] = {}, o2[16] = {};

        for (int m = 0; m < N_; m++) {
            float sc1 = 0.f, sc2 = 0.f;
#pragma unroll
            for (int j = 0; j < 8; j++) {
                sc1 += q[j] * Kl[m][j];
                sc2 += q[8 + j] * Kl[m][8 + j];
            }
            sc1 *= SCALE_S; sc2 *= SCALE_S;

            float nm1 = fmaxf(m1, sc1);
            float c1 = __expf(m1 - nm1), w1 = __expf(sc1 - nm1);
            s1 = s1 * c1 + w1; m1 = nm1;

            float nm2 = fmaxf(m2, sc2);
            float c2 = __expf(m2 - nm2), w2 = __expf(sc2 - nm2);
            s2 = s2 * c2 + w2; m2 = nm2;

#pragma unroll
            for (int e = 0; e < 16; e++) {
                float vv = Vl[m][e];
                o1[e] = o1[e] * c1 + w1 * vv;
                o2[e] = o2[e] * c2 + w2 * vv;
            }
        }

        float inv1 = 1.0f / s1, inv2 = lam / s2;
        float o[16]; float ss = 0.f;
#pragma unroll
        for (int e = 0; e < 16; e++) { o[e] = o1[e] * inv1 - o2[e] * inv2; ss += o[e] * o[e]; }
        float r = rsqrtf(ss * (1.0f / 16.0f) + EPS_);
        float* orow = st + ((size_t)bt * N_ + n) * 256 + h * 16;
#pragma unroll
        for (int e = 0; e < 16; e++) orow[e] = 0.8f * o[e] * r * subln[e];
    }
}

// ---------------------------------------------------------------------------
// DTW-aggregated spatial attention. Bilinear fold: qbar[n] = sum_c cmap[c,n]q[c],
// then standard attention over m in [0,C). One block per (bt,h).
// add=0: store, add=1: accumulate into sg.
// ---------------------------------------------------------------------------
template<int C>
__global__ __launch_bounds__(256) void agg_attn_kernel(
    const float* __restrict__ qb, const float* __restrict__ kb, const float* __restrict__ vb,
    const float* __restrict__ cmap, float* __restrict__ sg, int add)
{
    const int h = blockIdx.x % H_;
    const int bt = blockIdx.x / H_;
    __shared__ float ql[C][16], kl[C][16], vl[C][16];

    const float* qbase = qb + (size_t)bt * C * 64 + h * 16;
    const float* kbase = kb + (size_t)bt * C * 64 + h * 16;
    const float* vbase = vb + (size_t)bt * C * 64 + h * 16;
    for (int i = threadIdx.x; i < C * 16; i += 256) {
        int c = i >> 4, f = i & 15;
        ql[c][f] = qbase[(size_t)c * 64 + f];
        kl[c][f] = kbase[(size_t)c * 64 + f];
        vl[c][f] = vbase[(size_t)c * 64 + f];
    }
    __syncthreads();

    for (int n = threadIdx.x; n < N_; n += 256) {
        float qbar[16] = {};
        for (int c = 0; c < C; c++) {
            float w = cmap[(size_t)c * N_ + n];
#pragma unroll
            for (int f = 0; f < 16; f++) qbar[f] += w * ql[c][f];
        }
        float mx = -1e30f, sum = 0.f;
        float o[16] = {};
        for (int m = 0; m < C; m++) {
            float s = 0.f;
#pragma unroll
            for (int f = 0; f < 16; f++) s += qbar[f] * kl[m][f];
            s *= SCALE_H;
            float nm = fmaxf(mx, s);
            float cr = __expf(mx - nm), w = __expf(s - nm);
            sum = sum * cr + w; mx = nm;
#pragma unroll
            for (int f = 0; f < 16; f++) o[f] = o[f] * cr + w * vl[m][f];
        }
        float inv = 1.0f / sum;
        float* orow = sg + ((size_t)bt * N_ + n) * 64 + h * 16;
        if (add) {
#pragma unroll
            for (int f = 0; f < 16; f++) orow[f] += o[f] * inv;
        } else {
#pragma unroll
            for (int f = 0; f < 16; f++) orow[f] = o[f] * inv;
        }
    }
}

// ---------------------------------------------------------------------------
// Temporal attention: one thread per (b,n,h,t). T=12. Writes st channels [128,192).
// ---------------------------------------------------------------------------
__global__ __launch_bounds__(256) void temporal_kernel(
    const float* __restrict__ qt, const float* __restrict__ kt, const float* __restrict__ vt,
    float* __restrict__ st)
{
    int idx = blockIdx.x * 256 + threadIdx.x;
    int t = idx % T_;
    int h = (idx / T_) % H_;
    int n = (idx / (T_ * H_)) % N_;
    int b = idx / (T_ * H_ * N_);

    const float* qrow = qt + (((size_t)(b * T_ + t) * N_) + n) * 64 + h * 16;
    float q[16];
#pragma unroll
    for (int f = 0; f < 16; f++) q[f] = qrow[f];

    float sc[T_]; float mx = -1e30f;
    for (int u = 0; u < T_; u++) {
        const float* kr = kt + (((size_t)(b * T_ + u) * N_) + n) * 64 + h * 16;
        float s = 0.f;
#pragma unroll
        for (int f = 0; f < 16; f++) s += q[f] * kr[f];
        s *= SCALE_H;
        sc[u] = s; mx = fmaxf(mx, s);
    }
    float sum = 0.f;
    for (int u = 0; u < T_; u++) { sc[u] = __expf(sc[u] - mx); sum += sc[u]; }
    float inv = 1.0f / sum;
    float o[16] = {};
    for (int u = 0; u < T_; u++) {
        const float* vr = vt + (((size_t)(b * T_ + u) * N_) + n) * 64 + h * 16;
        float w = sc[u] * inv;
#pragma unroll
        for (int f = 0; f < 16; f++) o[f] += w * vr[f];
    }
    float* orow = st + (((size_t)(b * T_ + t) * N_) + n) * 256 + 128 + h * 16;
#pragma unroll
    for (int f = 0; f < 16; f++) orow[f] = o[f];
}

// ---------------------------------------------------------------------------
// Aggregative temporal attention: bilinear fold of tmp_inf into the query.
// qbar[f] = sum_s tmp_inf[b,n,t,s] * tq_param[n,s,h*16+f].
// One thread per (b,n,h,t). Writes st channels [192,256).
// ---------------------------------------------------------------------------
__global__ __launch_bounds__(256) void ta_kernel(
    const float* __restrict__ ka, const float* __restrict__ va,
    const float* __restrict__ tq, const float* __restrict__ ti,
    float* __restrict__ st)
{
    int idx = blockIdx.x * 256 + threadIdx.x;
    int t = idx % T_;
    int h = (idx / T_) % H_;
    int n = (idx / (T_ * H_)) % N_;
    int b = idx / (T_ * H_ * N_);

    float w[SEG_];
#pragma unroll
    for (int s = 0; s < SEG_; s++)
        w[s] = ti[(((size_t)b * N_ + n) * T_ + t) * SEG_ + s];

    float qbar[16] = {};
    for (int s = 0; s < SEG_; s++) {
        const float* qa = tq + ((size_t)n * SEG_ + s) * 64 + h * 16;
#pragma unroll
        for (int f = 0; f < 16; f++) qbar[f] += w[s] * qa[f];
    }

    float sc[T_]; float mx = -1e30f;
    for (int u = 0; u < T_; u++) {
        const float* kr = ka + (((size_t)(b * T_ + u) * N_) + n) * 64 + h * 16;
        float s = 0.f;
#pragma unroll
        for (int f = 0; f < 16; f++) s += qbar[f] * kr[f];
        s *= SCALE_H;
        sc[u] = s; mx = fmaxf(mx, s);
    }
    float sum = 0.f;
    for (int u = 0; u < T_; u++) { sc[u] = __expf(sc[u] - mx); sum += sc[u]; }
    float inv = 1.0f / sum;
    float o[16] = {};
    for (int u = 0; u < T_; u++) {
        const float* vr = va + (((size_t)(b * T_ + u) * N_) + n) * 64 + h * 16;
        float ww = sc[u] * inv;
#pragma unroll
        for (int f = 0; f < 16; f++) o[f] += ww * vr[f];
    }
    float* orow = st + (((size_t)(b * T_ + t) * N_) + n) * 256 + 192 + h * 16;
#pragma unroll
    for (int f = 0; f < 16; f++) orow[f] = o[f];
}

// ---------------------------------------------------------------------------
extern "C" void kernel_launch(void* const* d_in, const int* in_sizes, int n_in,
                              void* d_out, int out_size, void* d_ws, size_t ws_size,
                              hipStream_t stream)
{
    const float* x      = (const float*)d_in[0];
    const float* dtw0   = (const float*)d_in[1];
    const float* dtw1   = (const float*)d_in[2];
    const float* map0   = (const float*)d_in[3];
    const float* map1   = (const float*)d_in[4];
    const float* tmpinf = (const float*)d_in[5];
    const float* Wq_s   = (const float*)d_in[6];
    const float* Wk_s   = (const float*)d_in[7];
    const float* Wv_s   = (const float*)d_in[8];
    const float* lq1    = (const float*)d_in[9];
    const float* lk1    = (const float*)d_in[10];
    const float* lq2    = (const float*)d_in[11];
    const float* lk2    = (const float*)d_in[12];
    const float* subln  = (const float*)d_in[13];
    const float* Wq_a0  = (const float*)d_in[14];
    const float* Wk_a0  = (const float*)d_in[15];
    const float* Wv_a0  = (const float*)d_in[16];
    const float* Wq_a1  = (const float*)d_in[17];
    const float* Wk_a1  = (const float*)d_in[18];
    const float* Wv_a1  = (const float*)d_in[19];
    const float* W_agg  = (const float*)d_in[20];
    const float* b_agg  = (const float*)d_in[21];
    const float* Wq_t   = (const float*)d_in[22];
    const float* Wk_t   = (const float*)d_in[23];
    const float* Wv_t   = (const float*)d_in[24];
    const float* tq     = (const float*)d_in[25];
    const float* Wk_ta  = (const float*)d_in[26];
    const float* Wv_ta  = (const float*)d_in[27];
    const float* W_out  = (const float*)d_in[28];
    float* out = (float*)d_out;

    // workspace layout (floats)
    float* ws  = (float*)d_ws;
    float* st  = ws;                              // BT*N*256 = 6291456
    float* pa  = st + (size_t)BT_ * N_ * 256;     // 1572864 each
    float* pb  = pa + (size_t)BT_ * N_ * 64;
    float* pc  = pb + (size_t)BT_ * N_ * 64;
    float* qb_ = pc + (size_t)BT_ * N_ * 64;      // 393216 each (C=128 max)
    float* kb_ = qb_ + (size_t)BT_ * 128 * 64;
    float* vb_ = kb_ + (size_t)BT_ * 128 * 64;
    float* sgt = vb_ + (size_t)BT_ * 128 * 64;    // 1572864

    const int M = BT_ * N_;     // 24576
    dim3 blk(256);

    auto G = [&](const float* X, const float* W, const float* bias, float* O,
                 int Mm, int E, int K, int ldo, int ocol) {
        hipLaunchKernelGGL(gemm_xt, dim3(E / 64, Mm / 64), blk, 0, stream,
                           X, W, bias, O, Mm, E, K, ldo, ocol);
    };

    // ---- spatial differential attention ----
    G(x, Wq_s, nullptr, pa, M, 64, 256, 64, 0);
    G(x, Wk_s, nullptr, pb, M, 64, 256, 64, 0);
    G(x, Wv_s, nullptr, pc, M, 64, 256, 64, 0);
    hipLaunchKernelGGL(spatial_diff_kernel, dim3(BT_ * H_), blk, 0, stream,
                       pa, pb, pc, lq1, lk1, lq2, lk2, subln, st);

    // ---- dtw-aggregated spatial attention ----
    G(dtw0, Wq_a0, nullptr, qb_, BT_ * 64, 64, 256, 64, 0);
    G(dtw0, Wk_a0, nullptr, kb_, BT_ * 64, 64, 256, 64, 0);
    G(dtw0, Wv_a0, nullptr, vb_, BT_ * 64, 64, 256, 64, 0);
    hipLaunchKernelGGL((agg_attn_kernel<64>), dim3(BT_ * H_), blk, 0, stream,
                       qb_, kb_, vb_, map0, sgt, 0);

    G(dtw1, Wq_a1, nullptr, qb_, BT_ * 128, 64, 256, 64, 0);
    G(dtw1, Wk_a1, nullptr, kb_, BT_ * 128, 64, 256, 64, 0);
    G(dtw1, Wv_a1, nullptr, vb_, BT_ * 128, 64, 256, 64, 0);
    hipLaunchKernelGGL((agg_attn_kernel<128>), dim3(BT_ * H_), blk, 0, stream,
                       qb_, kb_, vb_, map1, sgt, 1);

    G(sgt, W_agg, b_agg, st, M, 64, 64, 256, 64);

    // ---- temporal attention ----
    G(x, Wq_t, nullptr, pa, M, 64, 256, 64, 0);
    G(x, Wk_t, nullptr, pb, M, 64, 256, 64, 0);
    G(x, Wv_t, nullptr, pc, M, 64, 256, 64, 0);
    hipLaunchKernelGGL(temporal_kernel, dim3(B_ * N_ * H_ * T_ / 256), blk, 0, stream,
                       pa, pb, pc, st);

    // ---- aggregative temporal attention ----
    G(x, Wk_ta, nullptr, pa, M, 64, 256, 64, 0);
    G(x, Wv_ta, nullptr, pb, M, 64, 256, 64, 0);
    hipLaunchKernelGGL(ta_kernel, dim3(B_ * N_ * H_ * T_ / 256), blk, 0, stream,
                       pa, pb, tq, tmpinf, st);

    // ---- output projection ----
    G(st, W_out, nullptr, out, M, 256, 256, 256, 0);
}

// Round 2
// 303.809 us; speedup vs baseline: 2.9191x; 2.9191x over previous
//
#include <hip/hip_runtime.h>
#include <hip/hip_bf16.h>
#include <cstddef>

#define B_ 4
#define T_ 12
#define N_ 512
#define D_ 256
#define H_ 4
#define SEG_ 6
#define BT_ (B_*T_)

#define SCALE_S 0.35355339059327373f   /* 8^-0.5  */
#define SCALE_H 0.25f                  /* 16^-0.5 */
#define LOG2E   1.44269504088896340736f
#define LAMBDA_INIT 0.2f
#define EPS_ 1e-6f

typedef short bf16x8 __attribute__((ext_vector_type(8)));
typedef float f32x4 __attribute__((ext_vector_type(4)));
typedef unsigned short us8 __attribute__((ext_vector_type(8)));
typedef unsigned short us4 __attribute__((ext_vector_type(4)));

__device__ inline float b2f(unsigned short u) {
    union { unsigned int i; float f; } x; x.i = ((unsigned int)u) << 16; return x.f;
}
__device__ inline unsigned short f2bs(float f) {
    __hip_bfloat16 b = __float2bfloat16(f);
    return *(unsigned short*)&b;
}
__device__ inline void load16(const unsigned short* p, float* f) {
    us8 a = *(const us8*)p; us8 b = *(const us8*)(p + 8);
#pragma unroll
    for (int r = 0; r < 8; r++) { f[r] = b2f(a[r]); f[8 + r] = b2f(b[r]); }
}

// ---------------------------------------------------------------------------
// fp32 -> bf16 conversion, 8 elems/thread. n must be a multiple of 8.
// ---------------------------------------------------------------------------
__global__ __launch_bounds__(256) void conv2bf16(
    const float* __restrict__ s, unsigned short* __restrict__ d, int n)
{
    int i = (blockIdx.x * 256 + threadIdx.x) * 8;
    if (i >= n) return;
    float4 a = *(const float4*)(s + i);
    float4 b = *(const float4*)(s + i + 4);
    us8 o;
    o[0] = f2bs(a.x); o[1] = f2bs(a.y); o[2] = f2bs(a.z); o[3] = f2bs(a.w);
    o[4] = f2bs(b.x); o[5] = f2bs(b.y); o[6] = f2bs(b.z); o[7] = f2bs(b.w);
    *(us8*)(d + i) = o;
}

// ---------------------------------------------------------------------------
// Convert + concat all weights to bf16.
// Layout (ushort elems): [0)   8 x [64,256]  proj weights (q_s,k_s,v_s,q_t,k_t,v_t,k_ta,v_ta)
//                        [131072) 3 x [64,256] dtw0 (q,k,v)
//                        [180224) 3 x [64,256] dtw1 (q,k,v)
//                        [229376) [64,64]  W_agg
//                        [233472) [256,256] W_out     total 299008
// ---------------------------------------------------------------------------
struct WPtrs { const float* p[16]; };
__global__ __launch_bounds__(256) void conv_weights(WPtrs wp, unsigned short* __restrict__ dst)
{
    int idx = blockIdx.x * 256 + threadIdx.x;
    if (idx >= 299008) return;
    const float* src; int rel;
    if (idx < 131072)      { src = wp.p[idx >> 14]; rel = idx & 16383; }
    else if (idx < 180224) { int r = idx - 131072; src = wp.p[8 + (r >> 14)]; rel = r & 16383; }
    else if (idx < 229376) { int r = idx - 180224; src = wp.p[11 + (r >> 14)]; rel = r & 16383; }
    else if (idx < 233472) { src = wp.p[14]; rel = idx - 229376; }
    else                   { src = wp.p[15]; rel = idx - 233472; }
    dst[idx] = f2bs(src[rel]);
}

// ---------------------------------------------------------------------------
// bf16 MFMA GEMM: O[m, ocol+e] = sum_k A[m,k] * W[e,k] (+bias[e])
// A: [M,K] bf16 row-major, W: [E,K] bf16 row-major.
// Tile: BM=128, BN=64, BK=64. 256 threads = 4 waves (2x2), wave = 64x32 out.
// M % 128 == 0, E % 64 == 0, K % 64 == 0.
// ---------------------------------------------------------------------------
template<bool OUT_BF16>
__global__ __launch_bounds__(256) void gemm_mfma(
    const unsigned short* __restrict__ A, const unsigned short* __restrict__ W,
    const float* __restrict__ bias, float* __restrict__ Of, unsigned short* __restrict__ Ob,
    int M, int E, int K, int ldo, int ocol)
{
    __shared__ unsigned short As[128 * 64];
    __shared__ unsigned short Ws[64 * 64];
    const int m0 = blockIdx.y * 128;
    const int e0 = blockIdx.x * 64;
    const int tid = threadIdx.x;
    const int lane = tid & 63;
    const int wid = tid >> 6;
    const int wm = wid >> 1, wn = wid & 1;
    const int l15 = lane & 15, l4 = lane >> 4;

    f32x4 acc[4][2];
#pragma unroll
    for (int i = 0; i < 4; i++)
#pragma unroll
        for (int j = 0; j < 2; j++)
#pragma unroll
            for (int r = 0; r < 4; r++) acc[i][j][r] = 0.f;

    for (int kk = 0; kk < K; kk += 64) {
#pragma unroll
        for (int p = 0; p < 4; p++) {
            int off = p * 2048 + tid * 8;
            int r = off >> 6, cc = off & 63;
            *(bf16x8*)(&As[off]) = *(const bf16x8*)(&A[(size_t)(m0 + r) * K + kk + cc]);
        }
#pragma unroll
        for (int p = 0; p < 2; p++) {
            int off = p * 2048 + tid * 8;
            int r = off >> 6, cc = off & 63;
            *(bf16x8*)(&Ws[off]) = *(const bf16x8*)(&W[(size_t)(e0 + r) * K + kk + cc]);
        }
        __syncthreads();
#pragma unroll
        for (int ks = 0; ks < 64; ks += 32) {
            bf16x8 af[4], bw[2];
#pragma unroll
            for (int i = 0; i < 4; i++)
                af[i] = *(bf16x8*)(&As[(wm * 64 + i * 16 + l15) * 64 + ks + l4 * 8]);
#pragma unroll
            for (int j = 0; j < 2; j++)
                bw[j] = *(bf16x8*)(&Ws[(wn * 32 + j * 16 + l15) * 64 + ks + l4 * 8]);
#pragma unroll
            for (int i = 0; i < 4; i++)
#pragma unroll
                for (int j = 0; j < 2; j++)
                    acc[i][j] = __builtin_amdgcn_mfma_f32_16x16x32_bf16(af[i], bw[j], acc[i][j], 0, 0, 0);
        }
        __syncthreads();
    }

#pragma unroll
    for (int i = 0; i < 4; i++)
#pragma unroll
        for (int j = 0; j < 2; j++) {
            int row0 = m0 + wm * 64 + i * 16 + l4 * 4;
            int col = ocol + e0 + wn * 32 + j * 16 + l15;
            float bv = bias ? bias[e0 + wn * 32 + j * 16 + l15] : 0.f;
#pragma unroll
            for (int r = 0; r < 4; r++) {
                float v = acc[i][j][r] + bv;
                if (OUT_BF16) Ob[(size_t)(row0 + r) * ldo + col] = f2bs(v);
                else          Of[(size_t)(row0 + r) * ldo + col] = v;
            }
        }
}

// ---------------------------------------------------------------------------
// Spatial differential attention v2.
// P: bf16 [BT*N, 512]; q at col 0, k at 64, v at 128 (+h*16).
// Grid: 1536 = 192 (bt,h) x 8 row-chunks of 64. Block 256 = 4 waves.
// Wave lane layout: 16 rows x 4 m-chunks (128 m each); shfl_xor merge.
// No max-tracking (scores bounded well below exp2 overflow).
// ---------------------------------------------------------------------------
__global__ __launch_bounds__(256) void spatial_diff_v2(
    const unsigned short* __restrict__ P,
    const float* __restrict__ lq1, const float* __restrict__ lk1,
    const float* __restrict__ lq2, const float* __restrict__ lk2,
    const float* __restrict__ subln, unsigned short* __restrict__ st)
{
    const int g = blockIdx.x >> 3;
    const int blkrow = (blockIdx.x & 7) * 64;
    const int h = g & 3, bt = g >> 2;

    __shared__ float4 Kl[N_][4];
    __shared__ float4 Vl[N_][4];

    const unsigned short* kb = P + ((size_t)bt * N_) * 512 + 64 + h * 16;
    const unsigned short* vb = P + ((size_t)bt * N_) * 512 + 128 + h * 16;
    for (int s = threadIdx.x; s < N_ * 4; s += 256) {
        int m = s >> 2, j = s & 3;
        us4 kr = *(const us4*)(kb + (size_t)m * 512 + j * 4);
        us4 vr = *(const us4*)(vb + (size_t)m * 512 + j * 4);
        float4 kf = { b2f(kr[0]), b2f(kr[1]), b2f(kr[2]), b2f(kr[3]) };
        float4 vf = { b2f(vr[0]), b2f(vr[1]), b2f(vr[2]), b2f(vr[3]) };
        int slot = (j + (m >> 7)) & 3;
        Kl[m][slot] = kf;
        Vl[m][slot] = vf;
    }
    __syncthreads();

    float e1 = 0.f, e2 = 0.f;
#pragma unroll
    for (int j = 0; j < 8; j++) { e1 += lq1[j] * lk1[j]; e2 += lq2[j] * lk2[j]; }
    const float lam = __expf(e1) - __expf(e2) + LAMBDA_INIT;

    const int lane = threadIdx.x & 63;
    const int w = threadIdx.x >> 6;
    const int rloc = lane & 15, c = lane >> 4;
    const int n = blkrow + w * 16 + rloc;

    float q[16];
    load16(P + ((size_t)bt * N_ + n) * 512 + h * 16, q);
#pragma unroll
    for (int j = 0; j < 16; j++) q[j] *= SCALE_S * LOG2E;

    float s1 = 0.f, s2 = 0.f;
    float o1[16] = {}, o2[16] = {};

    for (int i = 0; i < 128; i++) {
        int m = c * 128 + i;
        float4 ka = Kl[m][c & 3];
        float4 kb4 = Kl[m][(c + 1) & 3];
        float4 kc = Kl[m][(c + 2) & 3];
        float4 kd = Kl[m][(c + 3) & 3];
        float sc1 = q[0]*ka.x + q[1]*ka.y + q[2]*ka.z + q[3]*ka.w
                  + q[4]*kb4.x + q[5]*kb4.y + q[6]*kb4.z + q[7]*kb4.w;
        float sc2 = q[8]*kc.x + q[9]*kc.y + q[10]*kc.z + q[11]*kc.w
                  + q[12]*kd.x + q[13]*kd.y + q[14]*kd.z + q[15]*kd.w;
        float w1 = __builtin_amdgcn_exp2f(sc1);
        float w2 = __builtin_amdgcn_exp2f(sc2);
        s1 += w1; s2 += w2;
        float4 va = Vl[m][c & 3];
        float4 vb4 = Vl[m][(c + 1) & 3];
        float4 vc = Vl[m][(c + 2) & 3];
        float4 vd = Vl[m][(c + 3) & 3];
        o1[0] += w1*va.x;  o1[1] += w1*va.y;  o1[2] += w1*va.z;  o1[3] += w1*va.w;
        o1[4] += w1*vb4.x; o1[5] += w1*vb4.y; o1[6] += w1*vb4.z; o1[7] += w1*vb4.w;
        o1[8] += w1*vc.x;  o1[9] += w1*vc.y;  o1[10]+= w1*vc.z;  o1[11]+= w1*vc.w;
        o1[12]+= w1*vd.x;  o1[13]+= w1*vd.y;  o1[14]+= w1*vd.z;  o1[15]+= w1*vd.w;
        o2[0] += w2*va.x;  o2[1] += w2*va.y;  o2[2] += w2*va.z;  o2[3] += w2*va.w;
        o2[4] += w2*vb4.x; o2[5] += w2*vb4.y; o2[6] += w2*vb4.z; o2[7] += w2*vb4.w;
        o2[8] += w2*vc.x;  o2[9] += w2*vc.y;  o2[10]+= w2*vc.z;  o2[11]+= w2*vc.w;
        o2[12]+= w2*vd.x;  o2[13]+= w2*vd.y;  o2[14]+= w2*vd.z;  o2[15]+= w2*vd.w;
    }

#pragma unroll
    for (int mask = 16; mask <= 32; mask <<= 1) {
        s1 += __shfl_xor(s1, mask);
        s2 += __shfl_xor(s2, mask);
#pragma unroll
        for (int e = 0; e < 16; e++) {
            o1[e] += __shfl_xor(o1[e], mask);
            o2[e] += __shfl_xor(o2[e], mask);
        }
    }

    if (c == 0) {
        float inv1 = 1.0f / s1, inv2 = lam / s2;
        float o[16]; float ss = 0.f;
#pragma unroll
        for (int e = 0; e < 16; e++) { o[e] = o1[e] * inv1 - o2[e] * inv2; ss += o[e] * o[e]; }
        float r = rsqrtf(ss * (1.0f / 16.0f) + EPS_);
        unsigned short* orow = st + ((size_t)bt * N_ + n) * 256 + h * 16;
#pragma unroll
        for (int e = 0; e < 16; e++) orow[e] = f2bs(0.8f * o[e] * r * subln[e]);
    }
}

// ---------------------------------------------------------------------------
// DTW-aggregated spatial attention (fp32 qkv, stride ld=192).
// ---------------------------------------------------------------------------
template<int C>
__global__ __launch_bounds__(256) void agg_attn_kernel(
    const float* __restrict__ qkv, const float* __restrict__ cmap,
    float* __restrict__ sg, int add)
{
    const int h = blockIdx.x % H_;
    const int bt = blockIdx.x / H_;
    __shared__ float ql[C][16], kl[C][16], vl[C][16];

    const float* base = qkv + (size_t)bt * C * 192;
    for (int i = threadIdx.x; i < C * 16; i += 256) {
        int c = i >> 4, f = i & 15;
        ql[c][f] = base[(size_t)c * 192 + h * 16 + f];
        kl[c][f] = base[(size_t)c * 192 + 64 + h * 16 + f];
        vl[c][f] = base[(size_t)c * 192 + 128 + h * 16 + f];
    }
    __syncthreads();

    for (int n = threadIdx.x; n < N_; n += 256) {
        float qbar[16] = {};
        for (int c = 0; c < C; c++) {
            float w = cmap[(size_t)c * N_ + n];
#pragma unroll
            for (int f = 0; f < 16; f++) qbar[f] += w * ql[c][f];
        }
        float mx = -1e30f, sum = 0.f;
        float o[16] = {};
        for (int m = 0; m < C; m++) {
            float s = 0.f;
#pragma unroll
            for (int f = 0; f < 16; f++) s += qbar[f] * kl[m][f];
            s *= SCALE_H;
            float nm = fmaxf(mx, s);
            float cr = __expf(mx - nm), w = __expf(s - nm);
            sum = sum * cr + w; mx = nm;
#pragma unroll
            for (int f = 0; f < 16; f++) o[f] = o[f] * cr + w * vl[m][f];
        }
        float inv = 1.0f / sum;
        float* orow = sg + ((size_t)bt * N_ + n) * 64 + h * 16;
        if (add) {
#pragma unroll
            for (int f = 0; f < 16; f++) orow[f] += o[f] * inv;
        } else {
#pragma unroll
            for (int f = 0; f < 16; f++) orow[f] = o[f] * inv;
        }
    }
}

// ---------------------------------------------------------------------------
// Temporal attention: one thread per (b,n,h,t). Reads P cols 192/256/320.
// Writes st cols [128,192).
// ---------------------------------------------------------------------------
__global__ __launch_bounds__(256) void temporal_kernel(
    const unsigned short* __restrict__ P, unsigned short* __restrict__ st)
{
    int idx = blockIdx.x * 256 + threadIdx.x;
    int t = idx % T_;
    int h = (idx / T_) % H_;
    int n = (idx / (T_ * H_)) % N_;
    int b = idx / (T_ * H_ * N_);

    float q[16];
    load16(P + (((size_t)(b * T_ + t) * N_) + n) * 512 + 192 + h * 16, q);

    float sc[T_]; float mx = -1e30f;
    for (int u = 0; u < T_; u++) {
        float k[16];
        load16(P + (((size_t)(b * T_ + u) * N_) + n) * 512 + 256 + h * 16, k);
        float s = 0.f;
#pragma unroll
        for (int f = 0; f < 16; f++) s += q[f] * k[f];
        s *= SCALE_H;
        sc[u] = s; mx = fmaxf(mx, s);
    }
    float sum = 0.f;
    for (int u = 0; u < T_; u++) { sc[u] = __expf(sc[u] - mx); sum += sc[u]; }
    float inv = 1.0f / sum;
    float o[16] = {};
    for (int u = 0; u < T_; u++) {
        float v[16];
        load16(P + (((size_t)(b * T_ + u) * N_) + n) * 512 + 320 + h * 16, v);
        float w = sc[u] * inv;
#pragma unroll
        for (int f = 0; f < 16; f++) o[f] += w * v[f];
    }
    unsigned short* orow = st + (((size_t)(b * T_ + t) * N_) + n) * 256 + 128 + h * 16;
#pragma unroll
    for (int f = 0; f < 16; f++) orow[f] = f2bs(o[f]);
}

// ---------------------------------------------------------------------------
// Aggregative temporal attention: tmp_inf folded into query.
// Reads P cols 384 (k), 448 (v). Writes st cols [192,256).
// ---------------------------------------------------------------------------
__global__ __launch_bounds__(256) void ta_kernel(
    const unsigned short* __restrict__ P,
    const float* __restrict__ tq, const float* __restrict__ ti,
    unsigned short* __restrict__ st)
{
    int idx = blockIdx.x * 256 + threadIdx.x;
    int t = idx % T_;
    int h = (idx / T_) % H_;
    int n = (idx / (T_ * H_)) % N_;
    int b = idx / (T_ * H_ * N_);

    float w[SEG_];
#pragma unroll
    for (int s = 0; s < SEG_; s++)
        w[s] = ti[(((size_t)b * N_ + n) * T_ + t) * SEG_ + s];

    float qbar[16] = {};
    for (int s = 0; s < SEG_; s++) {
        const float* qa = tq + ((size_t)n * SEG_ + s) * 64 + h * 16;
#pragma unroll
        for (int f = 0; f < 16; f++) qbar[f] += w[s] * qa[f];
    }

    float sc[T_]; float mx = -1e30f;
    for (int u = 0; u < T_; u++) {
        float k[16];
        load16(P + (((size_t)(b * T_ + u) * N_) + n) * 512 + 384 + h * 16, k);
        float s = 0.f;
#pragma unroll
        for (int f = 0; f < 16; f++) s += qbar[f] * k[f];
        s *= SCALE_H;
        sc[u] = s; mx = fmaxf(mx, s);
    }
    float sum = 0.f;
    for (int u = 0; u < T_; u++) { sc[u] = __expf(sc[u] - mx); sum += sc[u]; }
    float inv = 1.0f / sum;
    float o[16] = {};
    for (int u = 0; u < T_; u++) {
        float v[16];
        load16(P + (((size_t)(b * T_ + u) * N_) + n) * 512 + 448 + h * 16, v);
        float ww = sc[u] * inv;
#pragma unroll
        for (int f = 0; f < 16; f++) o[f] += ww * v[f];
    }
    unsigned short* orow = st + (((size_t)(b * T_ + t) * N_) + n) * 256 + 192 + h * 16;
#pragma unroll
    for (int f = 0; f < 16; f++) orow[f] = f2bs(o[f]);
}

// ---------------------------------------------------------------------------
extern "C" void kernel_launch(void* const* d_in, const int* in_sizes, int n_in,
                              void* d_out, int out_size, void* d_ws, size_t ws_size,
                              hipStream_t stream)
{
    const float* x      = (const float*)d_in[0];
    const float* dtw0   = (const float*)d_in[1];
    const float* dtw1   = (const float*)d_in[2];
    const float* map0   = (const float*)d_in[3];
    const float* map1   = (const float*)d_in[4];
    const float* tmpinf = (const float*)d_in[5];
    const float* lq1    = (const float*)d_in[9];
    const float* lk1    = (const float*)d_in[10];
    const float* lq2    = (const float*)d_in[11];
    const float* lk2    = (const float*)d_in[12];
    const float* subln  = (const float*)d_in[13];
    const float* b_agg  = (const float*)d_in[21];
    const float* tq     = (const float*)d_in[25];
    float* out = (float*)d_out;

    const size_t M = (size_t)BT_ * N_;   // 24576

    // workspace layout (bytes, 256-aligned chunks)
    char* w = (char*)d_ws;
    unsigned short* P    = (unsigned short*)w;               w += M * 512 * 2;       // 25.2 MB
    unsigned short* st   = (unsigned short*)w;               w += M * 256 * 2;       // 12.6 MB
    float*          sgt  = (float*)w;                        w += M * 64 * 4;        // 6.3 MB
    float*          qkv0 = (float*)w;                        w += (size_t)BT_*64*192*4;  // 2.36 MB
    float*          qkv1 = (float*)w;                        w += (size_t)BT_*128*192*4; // 4.72 MB
    unsigned short* xb   = (unsigned short*)w;               w += M * 256 * 2;       // 12.6 MB
    unsigned short* d0b  = (unsigned short*)w;               w += (size_t)BT_*64*256*2;  // 1.57 MB
    unsigned short* d1b  = (unsigned short*)w;               w += (size_t)BT_*128*256*2; // 3.15 MB
    unsigned short* sgtb = (unsigned short*)w;               w += M * 64 * 2;        // 3.15 MB
    unsigned short* wb   = (unsigned short*)w;               w += 299008 * 2;        // 0.6 MB

    unsigned short* Wproj = wb;
    unsigned short* Wd0   = wb + 131072;
    unsigned short* Wd1   = wb + 180224;
    unsigned short* Wagg  = wb + 229376;
    unsigned short* Wout  = wb + 233472;

    dim3 blk(256);

    // 1-3. convert activations
    hipLaunchKernelGGL(conv2bf16, dim3(3072), blk, 0, stream, x, xb, (int)(M * 256));
    hipLaunchKernelGGL(conv2bf16, dim3(384),  blk, 0, stream, dtw0, d0b, BT_ * 64 * 256);
    hipLaunchKernelGGL(conv2bf16, dim3(768),  blk, 0, stream, dtw1, d1b, BT_ * 128 * 256);

    // 4. convert + concat weights
    WPtrs wp;
    wp.p[0] = (const float*)d_in[6];  wp.p[1] = (const float*)d_in[7];  wp.p[2] = (const float*)d_in[8];   // q_s,k_s,v_s
    wp.p[3] = (const float*)d_in[22]; wp.p[4] = (const float*)d_in[23]; wp.p[5] = (const float*)d_in[24];  // q_t,k_t,v_t
    wp.p[6] = (const float*)d_in[26]; wp.p[7] = (const float*)d_in[27];                                    // k_ta,v_ta
    wp.p[8] = (const float*)d_in[14]; wp.p[9] = (const float*)d_in[15]; wp.p[10] = (const float*)d_in[16]; // dtw0 qkv
    wp.p[11] = (const float*)d_in[17]; wp.p[12] = (const float*)d_in[18]; wp.p[13] = (const float*)d_in[19]; // dtw1 qkv
    wp.p[14] = (const float*)d_in[20];  // W_agg
    wp.p[15] = (const float*)d_in[28];  // W_out
    hipLaunchKernelGGL(conv_weights, dim3(1168), blk, 0, stream, wp, wb);

    // 5. fused projection GEMM: [24576,256] x [512,256]^T -> P bf16
    hipLaunchKernelGGL((gemm_mfma<true>), dim3(8, 192), blk, 0, stream,
                       xb, Wproj, (const float*)nullptr, (float*)nullptr, P,
                       (int)M, 512, 256, 512, 0);
    // 6-7. dtw projections -> fp32
    hipLaunchKernelGGL((gemm_mfma<false>), dim3(3, 24), blk, 0, stream,
                       d0b, Wd0, (const float*)nullptr, qkv0, (unsigned short*)nullptr,
                       BT_ * 64, 192, 256, 192, 0);
    hipLaunchKernelGGL((gemm_mfma<false>), dim3(3, 48), blk, 0, stream,
                       d1b, Wd1, (const float*)nullptr, qkv1, (unsigned short*)nullptr,
                       BT_ * 128, 192, 256, 192, 0);

    // 8. spatial differential attention -> st cols [0,64)
    hipLaunchKernelGGL(spatial_diff_v2, dim3(1536), blk, 0, stream,
                       P, lq1, lk1, lq2, lk2, subln, st);

    // 9-10. agg spatial attention -> sgt
    hipLaunchKernelGGL((agg_attn_kernel<64>),  dim3(BT_ * H_), blk, 0, stream, qkv0, map0, sgt, 0);
    hipLaunchKernelGGL((agg_attn_kernel<128>), dim3(BT_ * H_), blk, 0, stream, qkv1, map1, sgt, 1);

    // 11-12. sgt @ W_agg^T + b -> st cols [64,128)
    hipLaunchKernelGGL(conv2bf16, dim3(768), blk, 0, stream, sgt, sgtb, (int)(M * 64));
    hipLaunchKernelGGL((gemm_mfma<true>), dim3(1, 192), blk, 0, stream,
                       sgtb, Wagg, b_agg, (float*)nullptr, st,
                       (int)M, 64, 64, 256, 64);

    // 13-14. temporal + aggregative temporal -> st cols [128,256)
    hipLaunchKernelGGL(temporal_kernel, dim3(B_ * N_ * H_ * T_ / 256), blk, 0, stream, P, st);
    hipLaunchKernelGGL(ta_kernel, dim3(B_ * N_ * H_ * T_ / 256), blk, 0, stream, P, tq, tmpinf, st);

    // 15. output projection: st [24576,256] x [256,256]^T -> out fp32
    hipLaunchKernelGGL((gemm_mfma<false>), dim3(4, 192), blk, 0, stream,
                       st, Wout, (const float*)nullptr, out, (unsigned short*)nullptr,
                       (int)M, 256, 256, 256, 0);
}

// Round 3
// 178.335 us; speedup vs baseline: 4.9730x; 1.7036x over previous
//
#include <hip/hip_runtime.h>
#include <hip/hip_bf16.h>
#include <cstddef>

#define B_ 4
#define T_ 12
#define N_ 512
#define D_ 256
#define H_ 4
#define SEG_ 6
#define BT_ (B_*T_)

#define SCALE_S 0.35355339059327373f   /* 8^-0.5  */
#define SCALE_H 0.25f                  /* 16^-0.5 */
#define LOG2E   1.44269504088896340736f
#define LAMBDA_INIT 0.2f
#define EPS_ 1e-6f

typedef short bf16x8 __attribute__((ext_vector_type(8)));
typedef float f32x4 __attribute__((ext_vector_type(4)));
typedef unsigned short us8 __attribute__((ext_vector_type(8)));
typedef unsigned short us4 __attribute__((ext_vector_type(4)));

__device__ inline float b2f(unsigned short u) {
    union { unsigned int i; float f; } x; x.i = ((unsigned int)u) << 16; return x.f;
}
__device__ inline unsigned short f2bs(float f) {
    __hip_bfloat16 b = __float2bfloat16(f);
    return *(unsigned short*)&b;
}
__device__ inline void load16(const unsigned short* p, float* f) {
    us8 a = *(const us8*)p; us8 b = *(const us8*)(p + 8);
#pragma unroll
    for (int r = 0; r < 8; r++) { f[r] = b2f(a[r]); f[8 + r] = b2f(b[r]); }
}

// ---------------------------------------------------------------------------
// Fused fp32->bf16 conversion for all activations + weights (one launch).
// seg0: x (6291456) -> xb ; seg1: dtw0 (786432) -> d0b ; seg2: dtw1 (1572864)
// -> d1b ; seg3: 16 weight tensors concat (299008) -> wb.
// ---------------------------------------------------------------------------
struct ConvArgs {
    const float* x; const float* d0; const float* d1;
    const float* wp[16];
    unsigned short* xb; unsigned short* d0b; unsigned short* d1b; unsigned short* wb;
};
#define CSEG0 6291456
#define CSEG1 (CSEG0 + 786432)
#define CSEG2 (CSEG1 + 1572864)
#define CTOT  (CSEG2 + 299008)

__global__ __launch_bounds__(256) void conv_all(ConvArgs a)
{
    long long i = (long long)(blockIdx.x * 256 + threadIdx.x) * 8;
    if (i >= CTOT) return;
    const float* src; unsigned short* dst; long long rel;
    if (i < CSEG0)      { src = a.x;  dst = a.xb;  rel = i; }
    else if (i < CSEG1) { src = a.d0; dst = a.d0b; rel = i - CSEG0; }
    else if (i < CSEG2) { src = a.d1; dst = a.d1b; rel = i - CSEG1; }
    else {
        int widx = (int)(i - CSEG2);
#pragma unroll
        for (int k = 0; k < 8; k++) {
            int idx = widx + k;
            const float* s; int r;
            if (idx < 131072)      { s = a.wp[idx >> 14]; r = idx & 16383; }
            else if (idx < 180224) { int q = idx - 131072; s = a.wp[8 + (q >> 14)]; r = q & 16383; }
            else if (idx < 229376) { int q = idx - 180224; s = a.wp[11 + (q >> 14)]; r = q & 16383; }
            else if (idx < 233472) { s = a.wp[14]; r = idx - 229376; }
            else                   { s = a.wp[15]; r = idx - 233472; }
            a.wb[idx] = f2bs(s[r]);
        }
        return;
    }
    float4 v0 = *(const float4*)(src + rel);
    float4 v1 = *(const float4*)(src + rel + 4);
    us8 o;
    o[0] = f2bs(v0.x); o[1] = f2bs(v0.y); o[2] = f2bs(v0.z); o[3] = f2bs(v0.w);
    o[4] = f2bs(v1.x); o[5] = f2bs(v1.y); o[6] = f2bs(v1.z); o[7] = f2bs(v1.w);
    *(us8*)(dst + rel) = o;
}

// ---------------------------------------------------------------------------
// bf16 MFMA GEMM (grid: x = m-blocks of 128, y = e-blocks of 64).
// ---------------------------------------------------------------------------
template<bool OUT_BF16>
__global__ __launch_bounds__(256) void gemm_mfma(
    const unsigned short* __restrict__ A, const unsigned short* __restrict__ W,
    const float* __restrict__ bias, float* __restrict__ Of, unsigned short* __restrict__ Ob,
    int M, int E, int K, int ldo, int ocol)
{
    __shared__ unsigned short As[128 * 64];
    __shared__ unsigned short Ws[64 * 64];
    const int m0 = blockIdx.x * 128;
    const int e0 = blockIdx.y * 64;
    const int tid = threadIdx.x;
    const int lane = tid & 63;
    const int wid = tid >> 6;
    const int wm = wid >> 1, wn = wid & 1;
    const int l15 = lane & 15, l4 = lane >> 4;

    f32x4 acc[4][2];
#pragma unroll
    for (int i = 0; i < 4; i++)
#pragma unroll
        for (int j = 0; j < 2; j++)
#pragma unroll
            for (int r = 0; r < 4; r++) acc[i][j][r] = 0.f;

    for (int kk = 0; kk < K; kk += 64) {
#pragma unroll
        for (int p = 0; p < 4; p++) {
            int off = p * 2048 + tid * 8;
            int r = off >> 6, cc = off & 63;
            *(bf16x8*)(&As[off]) = *(const bf16x8*)(&A[(size_t)(m0 + r) * K + kk + cc]);
        }
#pragma unroll
        for (int p = 0; p < 2; p++) {
            int off = p * 2048 + tid * 8;
            int r = off >> 6, cc = off & 63;
            *(bf16x8*)(&Ws[off]) = *(const bf16x8*)(&W[(size_t)(e0 + r) * K + kk + cc]);
        }
        __syncthreads();
#pragma unroll
        for (int ks = 0; ks < 64; ks += 32) {
            bf16x8 af[4], bw[2];
#pragma unroll
            for (int i = 0; i < 4; i++)
                af[i] = *(bf16x8*)(&As[(wm * 64 + i * 16 + l15) * 64 + ks + l4 * 8]);
#pragma unroll
            for (int j = 0; j < 2; j++)
                bw[j] = *(bf16x8*)(&Ws[(wn * 32 + j * 16 + l15) * 64 + ks + l4 * 8]);
#pragma unroll
            for (int i = 0; i < 4; i++)
#pragma unroll
                for (int j = 0; j < 2; j++)
                    acc[i][j] = __builtin_amdgcn_mfma_f32_16x16x32_bf16(af[i], bw[j], acc[i][j], 0, 0, 0);
        }
        __syncthreads();
    }

#pragma unroll
    for (int i = 0; i < 4; i++)
#pragma unroll
        for (int j = 0; j < 2; j++) {
            int row0 = m0 + wm * 64 + i * 16 + l4 * 4;
            int col = ocol + e0 + wn * 32 + j * 16 + l15;
            float bv = bias ? bias[e0 + wn * 32 + j * 16 + l15] : 0.f;
#pragma unroll
            for (int r = 0; r < 4; r++) {
                float v = acc[i][j][r] + bv;
                if (OUT_BF16) Ob[(size_t)(row0 + r) * ldo + col] = f2bs(v);
                else          Of[(size_t)(row0 + r) * ldo + col] = v;
            }
        }
}

// ---------------------------------------------------------------------------
// Spatial differential attention v3 — MFMA.
// P: bf16 [BT*N,512], q@0, k@64, v@128 (+h*16). Grid 768 = 192 (bt,h) x 4
// q-chunks of 128 rows. Block 256 = 4 waves; wave = 32 q-rows (2 tiles).
// K in LDS pre-scaled by SCALE*LOG2E (stride 24); V transposed (stride 520);
// P bounced through per-wave LDS tile [32][40] between QK-MFMA and PV-MFMA.
// S1 = masked-K group0 MFMA, S2 = group1; bare exp2 (scores bounded).
// ---------------------------------------------------------------------------
__global__ __launch_bounds__(256) void spatial_mfma(
    const unsigned short* __restrict__ P,
    const float* __restrict__ lq1, const float* __restrict__ lk1,
    const float* __restrict__ lq2, const float* __restrict__ lk2,
    const float* __restrict__ subln, unsigned short* __restrict__ st)
{
    __shared__ unsigned short Kl[512][24];
    __shared__ unsigned short Vt[16][520];
    __shared__ unsigned short Pl[4][32][40];

    const int bid = blockIdx.x;
    const int bth = bid >> 2, qc = bid & 3;
    const int h = bth & 3, bt = bth >> 2;
    const int tid = threadIdx.x;

    // ---- stage K (scaled) and V^T ----
    const unsigned short* kbase = P + (size_t)bt * N_ * 512 + 64 + h * 16;
    const unsigned short* vbase = P + (size_t)bt * N_ * 512 + 128 + h * 16;
    const float kscale = SCALE_S * LOG2E;
    for (int i = tid; i < 512; i += 256) {
        us8 k0 = *(const us8*)(kbase + (size_t)i * 512);
        us8 k1 = *(const us8*)(kbase + (size_t)i * 512 + 8);
        us8 s0, s1;
#pragma unroll
        for (int r = 0; r < 8; r++) {
            s0[r] = f2bs(b2f(k0[r]) * kscale);
            s1[r] = f2bs(b2f(k1[r]) * kscale);
        }
        *(us8*)&Kl[i][0] = s0;
        *(us8*)&Kl[i][8] = s1;
        us8 v0 = *(const us8*)(vbase + (size_t)i * 512);
        us8 v1 = *(const us8*)(vbase + (size_t)i * 512 + 8);
#pragma unroll
        for (int e = 0; e < 8; e++) { Vt[e][i] = v0[e]; Vt[8 + e][i] = v1[e]; }
    }
    __syncthreads();

    float e1 = 0.f, e2 = 0.f;
#pragma unroll
    for (int j = 0; j < 8; j++) { e1 += lq1[j] * lk1[j]; e2 += lq2[j] * lk2[j]; }
    const float lam = __expf(e1) - __expf(e2) + LAMBDA_INIT;

    const int lane = tid & 63, w = tid >> 6;
    const int l15 = lane & 15, g = lane >> 4;
    const int q0 = qc * 128 + w * 32;

    // Q fragments (Y operand), raw (scale folded into K)
    bf16x8 qf[2];
#pragma unroll
    for (int qt = 0; qt < 2; qt++)
        qf[qt] = *(const bf16x8*)(P + ((size_t)bt * N_ + q0 + qt * 16 + l15) * 512 + h * 16 + (g & 1) * 8);

    const f32x4 z4 = {0.f, 0.f, 0.f, 0.f};
    const bf16x8 zb = {0, 0, 0, 0, 0, 0, 0, 0};
    f32x4 O1[2], O2[2];
#pragma unroll
    for (int qt = 0; qt < 2; qt++)
#pragma unroll
        for (int r = 0; r < 4; r++) { O1[qt][r] = 0.f; O2[qt][r] = 0.f; }
    float rs1[2] = {0.f, 0.f}, rs2[2] = {0.f, 0.f};

    for (int mc = 0; mc < 512; mc += 32) {
        bf16x8 kva = *(bf16x8*)&Kl[mc + l15][(g & 1) * 8];
        bf16x8 kvb = *(bf16x8*)&Kl[mc + 16 + l15][(g & 1) * 8];
        bf16x8 a1a = (g == 0) ? kva : zb, a2a = (g == 1) ? kva : zb;
        bf16x8 a1b = (g == 0) ? kvb : zb, a2b = (g == 1) ? kvb : zb;
        bf16x8 vf = *(bf16x8*)&Vt[l15][mc + g * 8];

        f32x4 s1a[2], s1b[2], s2a[2], s2b[2];
#pragma unroll
        for (int qt = 0; qt < 2; qt++) {
            s1a[qt] = __builtin_amdgcn_mfma_f32_16x16x32_bf16(a1a, qf[qt], z4, 0, 0, 0);
            s1b[qt] = __builtin_amdgcn_mfma_f32_16x16x32_bf16(a1b, qf[qt], z4, 0, 0, 0);
            s2a[qt] = __builtin_amdgcn_mfma_f32_16x16x32_bf16(a2a, qf[qt], z4, 0, 0, 0);
            s2b[qt] = __builtin_amdgcn_mfma_f32_16x16x32_bf16(a2b, qf[qt], z4, 0, 0, 0);
        }

        // ---- softmax-1: exp2, row-sums, pack, bounce, PV ----
#pragma unroll
        for (int qt = 0; qt < 2; qt++) {
            f32x4 p0, p1;
#pragma unroll
            for (int r = 0; r < 4; r++) {
                p0[r] = __builtin_amdgcn_exp2f(s1a[qt][r]);
                p1[r] = __builtin_amdgcn_exp2f(s1b[qt][r]);
            }
            rs1[qt] += p0[0] + p0[1] + p0[2] + p0[3] + p1[0] + p1[1] + p1[2] + p1[3];
            us4 w0, w1;
#pragma unroll
            for (int r = 0; r < 4; r++) { w0[r] = f2bs(p0[r]); w1[r] = f2bs(p1[r]); }
            *(us4*)&Pl[w][qt * 16 + l15][g * 4] = w0;
            *(us4*)&Pl[w][qt * 16 + l15][16 + g * 4] = w1;
        }
#pragma unroll
        for (int qt = 0; qt < 2; qt++) {
            bf16x8 pf = *(bf16x8*)&Pl[w][qt * 16 + l15][g * 8];
            O1[qt] = __builtin_amdgcn_mfma_f32_16x16x32_bf16(pf, vf, O1[qt], 0, 0, 0);
        }
        // ---- softmax-2 ----
#pragma unroll
        for (int qt = 0; qt < 2; qt++) {
            f32x4 p0, p1;
#pragma unroll
            for (int r = 0; r < 4; r++) {
                p0[r] = __builtin_amdgcn_exp2f(s2a[qt][r]);
                p1[r] = __builtin_amdgcn_exp2f(s2b[qt][r]);
            }
            rs2[qt] += p0[0] + p0[1] + p0[2] + p0[3] + p1[0] + p1[1] + p1[2] + p1[3];
            us4 w0, w1;
#pragma unroll
            for (int r = 0; r < 4; r++) { w0[r] = f2bs(p0[r]); w1[r] = f2bs(p1[r]); }
            *(us4*)&Pl[w][qt * 16 + l15][g * 4] = w0;
            *(us4*)&Pl[w][qt * 16 + l15][16 + g * 4] = w1;
        }
#pragma unroll
        for (int qt = 0; qt < 2; qt++) {
            bf16x8 pf = *(bf16x8*)&Pl[w][qt * 16 + l15][g * 8];
            O2[qt] = __builtin_amdgcn_mfma_f32_16x16x32_bf16(pf, vf, O2[qt], 0, 0, 0);
        }
    }

    // reduce row-sums across lane groups (m-partials live per g)
#pragma unroll
    for (int qt = 0; qt < 2; qt++) {
        rs1[qt] += __shfl_xor(rs1[qt], 16); rs1[qt] += __shfl_xor(rs1[qt], 32);
        rs2[qt] += __shfl_xor(rs2[qt], 16); rs2[qt] += __shfl_xor(rs2[qt], 32);
    }

    const float sw = subln[l15];
#pragma unroll
    for (int qt = 0; qt < 2; qt++) {
#pragma unroll
        for (int r = 0; r < 4; r++) {
            int qrow = g * 4 + r;
            float s1 = __shfl(rs1[qt], qrow);
            float s2 = __shfl(rs2[qt], qrow);
            float o = O1[qt][r] / s1 - lam * (O2[qt][r] / s2);
            float ss = o * o;
            ss += __shfl_xor(ss, 1); ss += __shfl_xor(ss, 2);
            ss += __shfl_xor(ss, 4); ss += __shfl_xor(ss, 8);
            float rms = rsqrtf(ss * (1.0f / 16.0f) + EPS_);
            float val = 0.8f * o * rms * sw;
            int q = q0 + qt * 16 + qrow;
            st[((size_t)bt * N_ + q) * 256 + h * 16 + l15] = f2bs(val);
        }
    }
}

// ---------------------------------------------------------------------------
// DTW-aggregated spatial attention (fp32 qkv, stride 192), bf16 output.
// Grid: (bt,h) x 4 n-quarters, block 128 (1 n per thread).
// ---------------------------------------------------------------------------
template<int C, int ADD>
__global__ __launch_bounds__(128) void agg_attn_kernel(
    const float* __restrict__ qkv, const float* __restrict__ cmap,
    unsigned short* __restrict__ sg)
{
    const int bid = blockIdx.x;
    const int bth = bid >> 2, nq = bid & 3;
    const int h = bth % H_;
    const int bt = bth / H_;
    __shared__ float ql[C][16], kl[C][16], vl[C][16];

    const float* base = qkv + (size_t)bt * C * 192;
    for (int i = threadIdx.x; i < C * 16; i += 128) {
        int c = i >> 4, f = i & 15;
        ql[c][f] = base[(size_t)c * 192 + h * 16 + f];
        kl[c][f] = base[(size_t)c * 192 + 64 + h * 16 + f];
        vl[c][f] = base[(size_t)c * 192 + 128 + h * 16 + f];
    }
    __syncthreads();

    const int n = nq * 128 + threadIdx.x;
    float qbar[16] = {};
    for (int c = 0; c < C; c++) {
        float wgt = cmap[(size_t)c * N_ + n];
#pragma unroll
        for (int f = 0; f < 16; f++) qbar[f] += wgt * ql[c][f];
    }
    float mx = -1e30f, sum = 0.f;
    float o[16] = {};
    for (int m = 0; m < C; m++) {
        float s = 0.f;
#pragma unroll
        for (int f = 0; f < 16; f++) s += qbar[f] * kl[m][f];
        s *= SCALE_H;
        float nm = fmaxf(mx, s);
        float cr = __expf(mx - nm), wgt = __expf(s - nm);
        sum = sum * cr + wgt; mx = nm;
#pragma unroll
        for (int f = 0; f < 16; f++) o[f] = o[f] * cr + wgt * vl[m][f];
    }
    float inv = 1.0f / sum;
    unsigned short* orow = sg + ((size_t)bt * N_ + n) * 64 + h * 16;
    us8 w0, w1;
    if (ADD) {
        us8 r0 = *(const us8*)orow, r1 = *(const us8*)(orow + 8);
#pragma unroll
        for (int f = 0; f < 8; f++) {
            w0[f] = f2bs(b2f(r0[f]) + o[f] * inv);
            w1[f] = f2bs(b2f(r1[f]) + o[8 + f] * inv);
        }
    } else {
#pragma unroll
        for (int f = 0; f < 8; f++) {
            w0[f] = f2bs(o[f] * inv);
            w1[f] = f2bs(o[8 + f] * inv);
        }
    }
    *(us8*)orow = w0;
    *(us8*)(orow + 8) = w1;
}

// ---------------------------------------------------------------------------
// Merged temporal (+ aggregative temporal) attention. Grid 768: first 384
// blocks = temporal (st cols [128,192)), rest = ta (st cols [192,256)).
// ---------------------------------------------------------------------------
__global__ __launch_bounds__(256) void tempta_kernel(
    const unsigned short* __restrict__ P,
    const float* __restrict__ tq, const float* __restrict__ ti,
    unsigned short* __restrict__ st)
{
    const int part = blockIdx.x >= 384;
    int idx = (blockIdx.x - (part ? 384 : 0)) * 256 + threadIdx.x;
    int t = idx % T_;
    int h = (idx / T_) % H_;
    int n = (idx / (T_ * H_)) % N_;
    int b = idx / (T_ * H_ * N_);

    float q[16];
    if (!part) {
        load16(P + (((size_t)(b * T_ + t) * N_) + n) * 512 + 192 + h * 16, q);
    } else {
        float wseg[SEG_];
#pragma unroll
        for (int s = 0; s < SEG_; s++)
            wseg[s] = ti[(((size_t)b * N_ + n) * T_ + t) * SEG_ + s];
#pragma unroll
        for (int f = 0; f < 16; f++) q[f] = 0.f;
        for (int s = 0; s < SEG_; s++) {
            const float* qa = tq + ((size_t)n * SEG_ + s) * 64 + h * 16;
#pragma unroll
            for (int f = 0; f < 16; f++) q[f] += wseg[s] * qa[f];
        }
    }
    const int kcol = part ? 384 : 256;
    const int vcol = part ? 448 : 320;

    float sc[T_]; float mx = -1e30f;
    for (int u = 0; u < T_; u++) {
        float k[16];
        load16(P + (((size_t)(b * T_ + u) * N_) + n) * 512 + kcol + h * 16, k);
        float s = 0.f;
#pragma unroll
        for (int f = 0; f < 16; f++) s += q[f] * k[f];
        s *= SCALE_H;
        sc[u] = s; mx = fmaxf(mx, s);
    }
    float sum = 0.f;
    for (int u = 0; u < T_; u++) { sc[u] = __expf(sc[u] - mx); sum += sc[u]; }
    float inv = 1.0f / sum;
    float o[16] = {};
    for (int u = 0; u < T_; u++) {
        float v[16];
        load16(P + (((size_t)(b * T_ + u) * N_) + n) * 512 + vcol + h * 16, v);
        float ww = sc[u] * inv;
#pragma unroll
        for (int f = 0; f < 16; f++) o[f] += ww * v[f];
    }
    unsigned short* orow = st + (((size_t)(b * T_ + t) * N_) + n) * 256 + (part ? 192 : 128) + h * 16;
#pragma unroll
    for (int f = 0; f < 16; f++) orow[f] = f2bs(o[f]);
}

// ---------------------------------------------------------------------------
extern "C" void kernel_launch(void* const* d_in, const int* in_sizes, int n_in,
                              void* d_out, int out_size, void* d_ws, size_t ws_size,
                              hipStream_t stream)
{
    const float* x      = (const float*)d_in[0];
    const float* dtw0   = (const float*)d_in[1];
    const float* dtw1   = (const float*)d_in[2];
    const float* map0   = (const float*)d_in[3];
    const float* map1   = (const float*)d_in[4];
    const float* tmpinf = (const float*)d_in[5];
    const float* lq1    = (const float*)d_in[9];
    const float* lk1    = (const float*)d_in[10];
    const float* lq2    = (const float*)d_in[11];
    const float* lk2    = (const float*)d_in[12];
    const float* subln  = (const float*)d_in[13];
    const float* b_agg  = (const float*)d_in[21];
    const float* tq     = (const float*)d_in[25];
    float* out = (float*)d_out;

    const size_t M = (size_t)BT_ * N_;   // 24576

    char* w = (char*)d_ws;
    unsigned short* P    = (unsigned short*)w;   w += M * 512 * 2;
    unsigned short* st   = (unsigned short*)w;   w += M * 256 * 2;
    float*          qkv0 = (float*)w;            w += (size_t)BT_ * 64 * 192 * 4;
    float*          qkv1 = (float*)w;            w += (size_t)BT_ * 128 * 192 * 4;
    unsigned short* xb   = (unsigned short*)w;   w += M * 256 * 2;
    unsigned short* d0b  = (unsigned short*)w;   w += (size_t)BT_ * 64 * 256 * 2;
    unsigned short* d1b  = (unsigned short*)w;   w += (size_t)BT_ * 128 * 256 * 2;
    unsigned short* sgtb = (unsigned short*)w;   w += M * 64 * 2;
    unsigned short* wb   = (unsigned short*)w;   w += 299008 * 2;

    unsigned short* Wproj = wb;
    unsigned short* Wd0   = wb + 131072;
    unsigned short* Wd1   = wb + 180224;
    unsigned short* Wagg  = wb + 229376;
    unsigned short* Wout  = wb + 233472;

    dim3 blk(256);

    // 1. all conversions
    ConvArgs ca;
    ca.x = x; ca.d0 = dtw0; ca.d1 = dtw1;
    ca.wp[0] = (const float*)d_in[6];  ca.wp[1] = (const float*)d_in[7];  ca.wp[2] = (const float*)d_in[8];
    ca.wp[3] = (const float*)d_in[22]; ca.wp[4] = (const float*)d_in[23]; ca.wp[5] = (const float*)d_in[24];
    ca.wp[6] = (const float*)d_in[26]; ca.wp[7] = (const float*)d_in[27];
    ca.wp[8] = (const float*)d_in[14]; ca.wp[9] = (const float*)d_in[15]; ca.wp[10] = (const float*)d_in[16];
    ca.wp[11] = (const float*)d_in[17]; ca.wp[12] = (const float*)d_in[18]; ca.wp[13] = (const float*)d_in[19];
    ca.wp[14] = (const float*)d_in[20]; ca.wp[15] = (const float*)d_in[28];
    ca.xb = xb; ca.d0b = d0b; ca.d1b = d1b; ca.wb = wb;
    hipLaunchKernelGGL(conv_all, dim3((CTOT / 8 + 255) / 256), blk, 0, stream, ca);

    // 2. fused projection GEMM -> P bf16
    hipLaunchKernelGGL((gemm_mfma<true>), dim3(192, 8), blk, 0, stream,
                       xb, Wproj, (const float*)nullptr, (float*)nullptr, P,
                       (int)M, 512, 256, 512, 0);

    // 3. spatial differential attention (MFMA) -> st cols [0,64)
    hipLaunchKernelGGL(spatial_mfma, dim3(768), blk, 0, stream,
                       P, lq1, lk1, lq2, lk2, subln, st);

    // 4-5. dtw projections -> fp32
    hipLaunchKernelGGL((gemm_mfma<false>), dim3(24, 3), blk, 0, stream,
                       d0b, Wd0, (const float*)nullptr, qkv0, (unsigned short*)nullptr,
                       BT_ * 64, 192, 256, 192, 0);
    hipLaunchKernelGGL((gemm_mfma<false>), dim3(48, 3), blk, 0, stream,
                       d1b, Wd1, (const float*)nullptr, qkv1, (unsigned short*)nullptr,
                       BT_ * 128, 192, 256, 192, 0);

    // 6-7. agg spatial attention -> sgtb (bf16)
    hipLaunchKernelGGL((agg_attn_kernel<64, 0>),  dim3(BT_ * H_ * 4), dim3(128), 0, stream, qkv0, map0, sgtb);
    hipLaunchKernelGGL((agg_attn_kernel<128, 1>), dim3(BT_ * H_ * 4), dim3(128), 0, stream, qkv1, map1, sgtb);

    // 8. sgtb @ W_agg^T + b -> st cols [64,128)
    hipLaunchKernelGGL((gemm_mfma<true>), dim3(192, 1), blk, 0, stream,
                       sgtb, Wagg, b_agg, (float*)nullptr, st,
                       (int)M, 64, 64, 256, 64);

    // 9. temporal + aggregative temporal -> st cols [128,256)
    hipLaunchKernelGGL(tempta_kernel, dim3(768), blk, 0, stream, P, tq, tmpinf, st);

    // 10. output projection
    hipLaunchKernelGGL((gemm_mfma<false>), dim3(192, 4), blk, 0, stream,
                       st, Wout, (const float*)nullptr, out, (unsigned short*)nullptr,
                       (int)M, 256, 256, 256, 0);
}

// Round 4
// 131.001 us; speedup vs baseline: 6.7698x; 1.3613x over previous
//
#include <hip/hip_runtime.h>
#include <hip/hip_bf16.h>
#include <cstddef>

#define B_ 4
#define T_ 12
#define N_ 512
#define D_ 256
#define H_ 4
#define SEG_ 6
#define BT_ (B_*T_)

#define SCALE_S 0.35355339059327373f   /* 8^-0.5  */
#define SCALE_H 0.25f                  /* 16^-0.5 */
#define LOG2E   1.44269504088896340736f
#define LAMBDA_INIT 0.2f
#define EPS_ 1e-6f

typedef short bf16x8 __attribute__((ext_vector_type(8)));
typedef float f32x4 __attribute__((ext_vector_type(4)));
typedef unsigned short us8 __attribute__((ext_vector_type(8)));
typedef unsigned short us4 __attribute__((ext_vector_type(4)));

__device__ inline float b2f(unsigned short u) {
    union { unsigned int i; float f; } x; x.i = ((unsigned int)u) << 16; return x.f;
}
__device__ inline unsigned short f2bs(float f) {
    __hip_bfloat16 b = __float2bfloat16(f);
    return *(unsigned short*)&b;
}
__device__ inline void load16(const unsigned short* p, float* f) {
    us8 a = *(const us8*)p; us8 b = *(const us8*)(p + 8);
#pragma unroll
    for (int r = 0; r < 8; r++) { f[r] = b2f(a[r]); f[8 + r] = b2f(b[r]); }
}

// ---------------------------------------------------------------------------
// Fused fp32->bf16 conversion for all activations + weights (one launch).
// ---------------------------------------------------------------------------
struct ConvArgs {
    const float* x; const float* d0; const float* d1;
    const float* wp[16];
    unsigned short* xb; unsigned short* d0b; unsigned short* d1b; unsigned short* wb;
};
#define CSEG0 6291456
#define CSEG1 (CSEG0 + 786432)
#define CSEG2 (CSEG1 + 1572864)
#define CTOT  (CSEG2 + 299008)

__global__ __launch_bounds__(256) void conv_all(ConvArgs a)
{
    long long i = (long long)(blockIdx.x * 256 + threadIdx.x) * 8;
    if (i >= CTOT) return;
    const float* src; unsigned short* dst; long long rel;
    if (i < CSEG0)      { src = a.x;  dst = a.xb;  rel = i; }
    else if (i < CSEG1) { src = a.d0; dst = a.d0b; rel = i - CSEG0; }
    else if (i < CSEG2) { src = a.d1; dst = a.d1b; rel = i - CSEG1; }
    else {
        int widx = (int)(i - CSEG2);
#pragma unroll
        for (int k = 0; k < 8; k++) {
            int idx = widx + k;
            const float* s; int r;
            if (idx < 131072)      { s = a.wp[idx >> 14]; r = idx & 16383; }
            else if (idx < 180224) { int q = idx - 131072; s = a.wp[8 + (q >> 14)]; r = q & 16383; }
            else if (idx < 229376) { int q = idx - 180224; s = a.wp[11 + (q >> 14)]; r = q & 16383; }
            else if (idx < 233472) { s = a.wp[14]; r = idx - 229376; }
            else                   { s = a.wp[15]; r = idx - 233472; }
            a.wb[idx] = f2bs(s[r]);
        }
        return;
    }
    float4 v0 = *(const float4*)(src + rel);
    float4 v1 = *(const float4*)(src + rel + 4);
    us8 o;
    o[0] = f2bs(v0.x); o[1] = f2bs(v0.y); o[2] = f2bs(v0.z); o[3] = f2bs(v0.w);
    o[4] = f2bs(v1.x); o[5] = f2bs(v1.y); o[6] = f2bs(v1.z); o[7] = f2bs(v1.w);
    *(us8*)(dst + rel) = o;
}

// ---------------------------------------------------------------------------
// bf16 MFMA GEMM (grid: x = m-blocks of 128, y = e-blocks of 64).
// ---------------------------------------------------------------------------
template<bool OUT_BF16>
__global__ __launch_bounds__(256) void gemm_mfma(
    const unsigned short* __restrict__ A, const unsigned short* __restrict__ W,
    const float* __restrict__ bias, float* __restrict__ Of, unsigned short* __restrict__ Ob,
    int M, int E, int K, int ldo, int ocol)
{
    __shared__ unsigned short As[128 * 64];
    __shared__ unsigned short Ws[64 * 64];
    const int m0 = blockIdx.x * 128;
    const int e0 = blockIdx.y * 64;
    const int tid = threadIdx.x;
    const int lane = tid & 63;
    const int wid = tid >> 6;
    const int wm = wid >> 1, wn = wid & 1;
    const int l15 = lane & 15, l4 = lane >> 4;

    f32x4 acc[4][2];
#pragma unroll
    for (int i = 0; i < 4; i++)
#pragma unroll
        for (int j = 0; j < 2; j++)
#pragma unroll
            for (int r = 0; r < 4; r++) acc[i][j][r] = 0.f;

    for (int kk = 0; kk < K; kk += 64) {
#pragma unroll
        for (int p = 0; p < 4; p++) {
            int off = p * 2048 + tid * 8;
            int r = off >> 6, cc = off & 63;
            *(bf16x8*)(&As[off]) = *(const bf16x8*)(&A[(size_t)(m0 + r) * K + kk + cc]);
        }
#pragma unroll
        for (int p = 0; p < 2; p++) {
            int off = p * 2048 + tid * 8;
            int r = off >> 6, cc = off & 63;
            *(bf16x8*)(&Ws[off]) = *(const bf16x8*)(&W[(size_t)(e0 + r) * K + kk + cc]);
        }
        __syncthreads();
#pragma unroll
        for (int ks = 0; ks < 64; ks += 32) {
            bf16x8 af[4], bw[2];
#pragma unroll
            for (int i = 0; i < 4; i++)
                af[i] = *(bf16x8*)(&As[(wm * 64 + i * 16 + l15) * 64 + ks + l4 * 8]);
#pragma unroll
            for (int j = 0; j < 2; j++)
                bw[j] = *(bf16x8*)(&Ws[(wn * 32 + j * 16 + l15) * 64 + ks + l4 * 8]);
#pragma unroll
            for (int i = 0; i < 4; i++)
#pragma unroll
                for (int j = 0; j < 2; j++)
                    acc[i][j] = __builtin_amdgcn_mfma_f32_16x16x32_bf16(af[i], bw[j], acc[i][j], 0, 0, 0);
        }
        __syncthreads();
    }

#pragma unroll
    for (int i = 0; i < 4; i++)
#pragma unroll
        for (int j = 0; j < 2; j++) {
            int row0 = m0 + wm * 64 + i * 16 + l4 * 4;
            int col = ocol + e0 + wn * 32 + j * 16 + l15;
            float bv = bias ? bias[e0 + wn * 32 + j * 16 + l15] : 0.f;
#pragma unroll
            for (int r = 0; r < 4; r++) {
                float v = acc[i][j][r] + bv;
                if (OUT_BF16) Ob[(size_t)(row0 + r) * ldo + col] = f2bs(v);
                else          Of[(size_t)(row0 + r) * ldo + col] = v;
            }
        }
}

// ---------------------------------------------------------------------------
// Spatial differential attention (MFMA) — unchanged from round 3.
// ---------------------------------------------------------------------------
__global__ __launch_bounds__(256) void spatial_mfma(
    const unsigned short* __restrict__ P,
    const float* __restrict__ lq1, const float* __restrict__ lk1,
    const float* __restrict__ lq2, const float* __restrict__ lk2,
    const float* __restrict__ subln, unsigned short* __restrict__ st)
{
    __shared__ unsigned short Kl[512][24];
    __shared__ unsigned short Vt[16][520];
    __shared__ unsigned short Pl[4][32][40];

    const int bid = blockIdx.x;
    const int bth = bid >> 2, qc = bid & 3;
    const int h = bth & 3, bt = bth >> 2;
    const int tid = threadIdx.x;

    const unsigned short* kbase = P + (size_t)bt * N_ * 512 + 64 + h * 16;
    const unsigned short* vbase = P + (size_t)bt * N_ * 512 + 128 + h * 16;
    const float kscale = SCALE_S * LOG2E;
    for (int i = tid; i < 512; i += 256) {
        us8 k0 = *(const us8*)(kbase + (size_t)i * 512);
        us8 k1 = *(const us8*)(kbase + (size_t)i * 512 + 8);
        us8 s0, s1;
#pragma unroll
        for (int r = 0; r < 8; r++) {
            s0[r] = f2bs(b2f(k0[r]) * kscale);
            s1[r] = f2bs(b2f(k1[r]) * kscale);
        }
        *(us8*)&Kl[i][0] = s0;
        *(us8*)&Kl[i][8] = s1;
        us8 v0 = *(const us8*)(vbase + (size_t)i * 512);
        us8 v1 = *(const us8*)(vbase + (size_t)i * 512 + 8);
#pragma unroll
        for (int e = 0; e < 8; e++) { Vt[e][i] = v0[e]; Vt[8 + e][i] = v1[e]; }
    }
    __syncthreads();

    float e1 = 0.f, e2 = 0.f;
#pragma unroll
    for (int j = 0; j < 8; j++) { e1 += lq1[j] * lk1[j]; e2 += lq2[j] * lk2[j]; }
    const float lam = __expf(e1) - __expf(e2) + LAMBDA_INIT;

    const int lane = tid & 63, w = tid >> 6;
    const int l15 = lane & 15, g = lane >> 4;
    const int q0 = qc * 128 + w * 32;

    bf16x8 qf[2];
#pragma unroll
    for (int qt = 0; qt < 2; qt++)
        qf[qt] = *(const bf16x8*)(P + ((size_t)bt * N_ + q0 + qt * 16 + l15) * 512 + h * 16 + (g & 1) * 8);

    const f32x4 z4 = {0.f, 0.f, 0.f, 0.f};
    const bf16x8 zb = {0, 0, 0, 0, 0, 0, 0, 0};
    f32x4 O1[2], O2[2];
#pragma unroll
    for (int qt = 0; qt < 2; qt++)
#pragma unroll
        for (int r = 0; r < 4; r++) { O1[qt][r] = 0.f; O2[qt][r] = 0.f; }
    float rs1[2] = {0.f, 0.f}, rs2[2] = {0.f, 0.f};

    for (int mc = 0; mc < 512; mc += 32) {
        bf16x8 kva = *(bf16x8*)&Kl[mc + l15][(g & 1) * 8];
        bf16x8 kvb = *(bf16x8*)&Kl[mc + 16 + l15][(g & 1) * 8];
        bf16x8 a1a = (g == 0) ? kva : zb, a2a = (g == 1) ? kva : zb;
        bf16x8 a1b = (g == 0) ? kvb : zb, a2b = (g == 1) ? kvb : zb;
        bf16x8 vf = *(bf16x8*)&Vt[l15][mc + g * 8];

        f32x4 s1a[2], s1b[2], s2a[2], s2b[2];
#pragma unroll
        for (int qt = 0; qt < 2; qt++) {
            s1a[qt] = __builtin_amdgcn_mfma_f32_16x16x32_bf16(a1a, qf[qt], z4, 0, 0, 0);
            s1b[qt] = __builtin_amdgcn_mfma_f32_16x16x32_bf16(a1b, qf[qt], z4, 0, 0, 0);
            s2a[qt] = __builtin_amdgcn_mfma_f32_16x16x32_bf16(a2a, qf[qt], z4, 0, 0, 0);
            s2b[qt] = __builtin_amdgcn_mfma_f32_16x16x32_bf16(a2b, qf[qt], z4, 0, 0, 0);
        }

#pragma unroll
        for (int qt = 0; qt < 2; qt++) {
            f32x4 p0, p1;
#pragma unroll
            for (int r = 0; r < 4; r++) {
                p0[r] = __builtin_amdgcn_exp2f(s1a[qt][r]);
                p1[r] = __builtin_amdgcn_exp2f(s1b[qt][r]);
            }
            rs1[qt] += p0[0] + p0[1] + p0[2] + p0[3] + p1[0] + p1[1] + p1[2] + p1[3];
            us4 w0, w1;
#pragma unroll
            for (int r = 0; r < 4; r++) { w0[r] = f2bs(p0[r]); w1[r] = f2bs(p1[r]); }
            *(us4*)&Pl[w][qt * 16 + l15][g * 4] = w0;
            *(us4*)&Pl[w][qt * 16 + l15][16 + g * 4] = w1;
        }
#pragma unroll
        for (int qt = 0; qt < 2; qt++) {
            bf16x8 pf = *(bf16x8*)&Pl[w][qt * 16 + l15][g * 8];
            O1[qt] = __builtin_amdgcn_mfma_f32_16x16x32_bf16(pf, vf, O1[qt], 0, 0, 0);
        }
#pragma unroll
        for (int qt = 0; qt < 2; qt++) {
            f32x4 p0, p1;
#pragma unroll
            for (int r = 0; r < 4; r++) {
                p0[r] = __builtin_amdgcn_exp2f(s2a[qt][r]);
                p1[r] = __builtin_amdgcn_exp2f(s2b[qt][r]);
            }
            rs2[qt] += p0[0] + p0[1] + p0[2] + p0[3] + p1[0] + p1[1] + p1[2] + p1[3];
            us4 w0, w1;
#pragma unroll
            for (int r = 0; r < 4; r++) { w0[r] = f2bs(p0[r]); w1[r] = f2bs(p1[r]); }
            *(us4*)&Pl[w][qt * 16 + l15][g * 4] = w0;
            *(us4*)&Pl[w][qt * 16 + l15][16 + g * 4] = w1;
        }
#pragma unroll
        for (int qt = 0; qt < 2; qt++) {
            bf16x8 pf = *(bf16x8*)&Pl[w][qt * 16 + l15][g * 8];
            O2[qt] = __builtin_amdgcn_mfma_f32_16x16x32_bf16(pf, vf, O2[qt], 0, 0, 0);
        }
    }

#pragma unroll
    for (int qt = 0; qt < 2; qt++) {
        rs1[qt] += __shfl_xor(rs1[qt], 16); rs1[qt] += __shfl_xor(rs1[qt], 32);
        rs2[qt] += __shfl_xor(rs2[qt], 16); rs2[qt] += __shfl_xor(rs2[qt], 32);
    }

    const float sw = subln[l15];
#pragma unroll
    for (int qt = 0; qt < 2; qt++) {
#pragma unroll
        for (int r = 0; r < 4; r++) {
            int qrow = g * 4 + r;
            float s1 = __shfl(rs1[qt], qrow);
            float s2 = __shfl(rs2[qt], qrow);
            float o = O1[qt][r] / s1 - lam * (O2[qt][r] / s2);
            float ss = o * o;
            ss += __shfl_xor(ss, 1); ss += __shfl_xor(ss, 2);
            ss += __shfl_xor(ss, 4); ss += __shfl_xor(ss, 8);
            float rms = rsqrtf(ss * (1.0f / 16.0f) + EPS_);
            float val = 0.8f * o * rms * sw;
            int q = q0 + qt * 16 + qrow;
            st[((size_t)bt * N_ + q) * 256 + h * 16 + l15] = f2bs(val);
        }
    }
}

// ---------------------------------------------------------------------------
// DTW-aggregated spatial attention (MFMA), both maps fused.
// Grid 768 = 192 (bt,h) x 4 n-chunks of 128. Block 256 = 4 waves (32 n each).
// Per phase (C=64 then C=128):
//   stage cmapT [128 n][C] bf16, k [C][32-pad] (f 16 + zeros), qT/vT [16][C];
//   qbar = MFMA(cmapT, qT) over K=c; scale*log2e folded; bounce to Qb;
//   QK = MFMA(k, qbar) K=f(16+16z); bare exp2; P-bounce (aliases cmapT); PV MFMA.
// Register-accumulated across phases; single bf16 write to sgtb.
// LDS: T 17408us | Kf 5120 | Vt 2176 | QT 2176 | Qb 5120 = 32000 us = 64000 B.
// ---------------------------------------------------------------------------
template<int C>
__device__ inline void agg_phase(
    const unsigned short* __restrict__ qkv, const float* __restrict__ cmap,
    unsigned short* SH, int bt, int h, int nq,
    int tid, int w, int l15, int g, float oacc[2][4])
{
    unsigned short* T  = SH;            // [128][136]
    unsigned short* Kf = SH + 17408;    // [128][40]  (f 16 real + 16 zero, pad 8)
    unsigned short* Vt = SH + 22528;    // [16][136]
    unsigned short* QT = SH + 24704;    // [16][136]
    unsigned short* Qb = SH + 26880;    // [128][40]  (per-wave 32-row slices)

    // stage cmapT chunk (coalesced fp32 reads along n)
    for (int i = tid; i < C * 128; i += 256) {
        int c = i >> 7, nn = i & 127;
        T[nn * 136 + c] = f2bs(cmap[(size_t)c * 512 + nq * 128 + nn]);
    }
    // stage k (zero-padded), qT, vT
    const us8 z8 = {0, 0, 0, 0, 0, 0, 0, 0};
    for (int i = tid; i < C * 2; i += 256) {
        int c = i >> 1, hf = i & 1;
        const unsigned short* base = qkv + ((size_t)(bt * C + c)) * 192 + h * 16 + hf * 8;
        us8 qv = *(const us8*)(base);
        us8 kv = *(const us8*)(base + 64);
        us8 vv = *(const us8*)(base + 128);
        *(us8*)&Kf[c * 40 + hf * 8] = kv;
        *(us8*)&Kf[c * 40 + 16 + hf * 8] = z8;
#pragma unroll
        for (int e = 0; e < 8; e++) {
            QT[(hf * 8 + e) * 136 + c] = qv[e];
            Vt[(hf * 8 + e) * 136 + c] = vv[e];
        }
    }
    __syncthreads();

    // qbar = cmapT @ q  (K = c)
    const f32x4 z4 = {0.f, 0.f, 0.f, 0.f};
    f32x4 qac[2] = {z4, z4};
    for (int kk = 0; kk < C; kk += 32) {
        bf16x8 bwq = *(bf16x8*)&QT[l15 * 136 + kk + g * 8];
#pragma unroll
        for (int qt = 0; qt < 2; qt++) {
            bf16x8 af = *(bf16x8*)&T[(w * 32 + qt * 16 + l15) * 136 + kk + g * 8];
            qac[qt] = __builtin_amdgcn_mfma_f32_16x16x32_bf16(af, bwq, qac[qt], 0, 0, 0);
        }
    }
    const float qs = SCALE_H * LOG2E;
#pragma unroll
    for (int qt = 0; qt < 2; qt++)
#pragma unroll
        for (int r = 0; r < 4; r++) {
            int row = w * 32 + qt * 16 + g * 4 + r;
            Qb[row * 40 + l15] = f2bs(qac[qt][r] * qs);
            Qb[row * 40 + 16 + l15] = 0;
        }
    __syncthreads();   // T reads done; safe to alias as P-bounce

    unsigned short* Pl = SH;  // [128][40] aliases T
    f32x4 O[2] = {z4, z4};
    float rs[2] = {0.f, 0.f};

    for (int mc = 0; mc < C; mc += 32) {
        bf16x8 kva = *(bf16x8*)&Kf[(mc + l15) * 40 + g * 8];
        bf16x8 kvb = *(bf16x8*)&Kf[(mc + 16 + l15) * 40 + g * 8];
        bf16x8 vf  = *(bf16x8*)&Vt[l15 * 136 + mc + g * 8];
#pragma unroll
        for (int qt = 0; qt < 2; qt++) {
            bf16x8 qf2 = *(bf16x8*)&Qb[(w * 32 + qt * 16 + l15) * 40 + g * 8];
            f32x4 sa = __builtin_amdgcn_mfma_f32_16x16x32_bf16(kva, qf2, z4, 0, 0, 0);
            f32x4 sb = __builtin_amdgcn_mfma_f32_16x16x32_bf16(kvb, qf2, z4, 0, 0, 0);
            f32x4 pa, pb;
#pragma unroll
            for (int r = 0; r < 4; r++) {
                pa[r] = __builtin_amdgcn_exp2f(sa[r]);
                pb[r] = __builtin_amdgcn_exp2f(sb[r]);
            }
            rs[qt] += pa[0] + pa[1] + pa[2] + pa[3] + pb[0] + pb[1] + pb[2] + pb[3];
            us4 wa, wb2;
#pragma unroll
            for (int r = 0; r < 4; r++) { wa[r] = f2bs(pa[r]); wb2[r] = f2bs(pb[r]); }
            *(us4*)&Pl[(w * 32 + qt * 16 + l15) * 40 + g * 4] = wa;
            *(us4*)&Pl[(w * 32 + qt * 16 + l15) * 40 + 16 + g * 4] = wb2;
        }
#pragma unroll
        for (int qt = 0; qt < 2; qt++) {
            bf16x8 pf = *(bf16x8*)&Pl[(w * 32 + qt * 16 + l15) * 40 + g * 8];
            O[qt] = __builtin_amdgcn_mfma_f32_16x16x32_bf16(pf, vf, O[qt], 0, 0, 0);
        }
    }

#pragma unroll
    for (int qt = 0; qt < 2; qt++) {
        rs[qt] += __shfl_xor(rs[qt], 16);
        rs[qt] += __shfl_xor(rs[qt], 32);
    }
#pragma unroll
    for (int qt = 0; qt < 2; qt++)
#pragma unroll
        for (int r = 0; r < 4; r++) {
            float sum = __shfl(rs[qt], g * 4 + r);
            oacc[qt][r] += O[qt][r] / sum;
        }
    __syncthreads();   // before next phase restages
}

__global__ __launch_bounds__(256) void agg_mfma(
    const unsigned short* __restrict__ qkv0, const unsigned short* __restrict__ qkv1,
    const float* __restrict__ map0, const float* __restrict__ map1,
    unsigned short* __restrict__ sgtb)
{
    __shared__ unsigned short SH[32000];
    const int bid = blockIdx.x;
    const int bth = bid >> 2, nq = bid & 3;
    const int h = bth & 3, bt = bth >> 2;
    const int tid = threadIdx.x;
    const int lane = tid & 63, w = tid >> 6;
    const int l15 = lane & 15, g = lane >> 4;

    float oacc[2][4] = {};
    agg_phase<64>(qkv0, map0, SH, bt, h, nq, tid, w, l15, g, oacc);
    agg_phase<128>(qkv1, map1, SH, bt, h, nq, tid, w, l15, g, oacc);

#pragma unroll
    for (int qt = 0; qt < 2; qt++)
#pragma unroll
        for (int r = 0; r < 4; r++) {
            int n = nq * 128 + w * 32 + qt * 16 + g * 4 + r;
            sgtb[((size_t)(bt * N_ + n)) * 64 + h * 16 + l15] = f2bs(oacc[qt][r]);
        }
}

// ---------------------------------------------------------------------------
// Merged temporal (+ aggregative temporal) attention.
// ---------------------------------------------------------------------------
__global__ __launch_bounds__(256) void tempta_kernel(
    const unsigned short* __restrict__ P,
    const float* __restrict__ tq, const float* __restrict__ ti,
    unsigned short* __restrict__ st)
{
    const int part = blockIdx.x >= 384;
    int idx = (blockIdx.x - (part ? 384 : 0)) * 256 + threadIdx.x;
    int t = idx % T_;
    int h = (idx / T_) % H_;
    int n = (idx / (T_ * H_)) % N_;
    int b = idx / (T_ * H_ * N_);

    float q[16];
    if (!part) {
        load16(P + (((size_t)(b * T_ + t) * N_) + n) * 512 + 192 + h * 16, q);
    } else {
        float wseg[SEG_];
#pragma unroll
        for (int s = 0; s < SEG_; s++)
            wseg[s] = ti[(((size_t)b * N_ + n) * T_ + t) * SEG_ + s];
#pragma unroll
        for (int f = 0; f < 16; f++) q[f] = 0.f;
        for (int s = 0; s < SEG_; s++) {
            const float* qa = tq + ((size_t)n * SEG_ + s) * 64 + h * 16;
#pragma unroll
            for (int f = 0; f < 16; f++) q[f] += wseg[s] * qa[f];
        }
    }
    const int kcol = part ? 384 : 256;
    const int vcol = part ? 448 : 320;

    float sc[T_]; float mx = -1e30f;
    for (int u = 0; u < T_; u++) {
        float k[16];
        load16(P + (((size_t)(b * T_ + u) * N_) + n) * 512 + kcol + h * 16, k);
        float s = 0.f;
#pragma unroll
        for (int f = 0; f < 16; f++) s += q[f] * k[f];
        s *= SCALE_H;
        sc[u] = s; mx = fmaxf(mx, s);
    }
    float sum = 0.f;
    for (int u = 0; u < T_; u++) { sc[u] = __expf(sc[u] - mx); sum += sc[u]; }
    float inv = 1.0f / sum;
    float o[16] = {};
    for (int u = 0; u < T_; u++) {
        float v[16];
        load16(P + (((size_t)(b * T_ + u) * N_) + n) * 512 + vcol + h * 16, v);
        float ww = sc[u] * inv;
#pragma unroll
        for (int f = 0; f < 16; f++) o[f] += ww * v[f];
    }
    unsigned short* orow = st + (((size_t)(b * T_ + t) * N_) + n) * 256 + (part ? 192 : 128) + h * 16;
#pragma unroll
    for (int f = 0; f < 16; f++) orow[f] = f2bs(o[f]);
}

// ---------------------------------------------------------------------------
extern "C" void kernel_launch(void* const* d_in, const int* in_sizes, int n_in,
                              void* d_out, int out_size, void* d_ws, size_t ws_size,
                              hipStream_t stream)
{
    const float* x      = (const float*)d_in[0];
    const float* dtw0   = (const float*)d_in[1];
    const float* dtw1   = (const float*)d_in[2];
    const float* map0   = (const float*)d_in[3];
    const float* map1   = (const float*)d_in[4];
    const float* tmpinf = (const float*)d_in[5];
    const float* lq1    = (const float*)d_in[9];
    const float* lk1    = (const float*)d_in[10];
    const float* lq2    = (const float*)d_in[11];
    const float* lk2    = (const float*)d_in[12];
    const float* subln  = (const float*)d_in[13];
    const float* b_agg  = (const float*)d_in[21];
    const float* tq     = (const float*)d_in[25];
    float* out = (float*)d_out;

    const size_t M = (size_t)BT_ * N_;   // 24576

    char* w = (char*)d_ws;
    unsigned short* P     = (unsigned short*)w;   w += M * 512 * 2;
    unsigned short* st    = (unsigned short*)w;   w += M * 256 * 2;
    unsigned short* qkv0b = (unsigned short*)w;   w += (size_t)BT_ * 64 * 192 * 2;
    unsigned short* qkv1b = (unsigned short*)w;   w += (size_t)BT_ * 128 * 192 * 2;
    unsigned short* xb    = (unsigned short*)w;   w += M * 256 * 2;
    unsigned short* d0b   = (unsigned short*)w;   w += (size_t)BT_ * 64 * 256 * 2;
    unsigned short* d1b   = (unsigned short*)w;   w += (size_t)BT_ * 128 * 256 * 2;
    unsigned short* sgtb  = (unsigned short*)w;   w += M * 64 * 2;
    unsigned short* wb    = (unsigned short*)w;   w += 299008 * 2;

    unsigned short* Wproj = wb;
    unsigned short* Wd0   = wb + 131072;
    unsigned short* Wd1   = wb + 180224;
    unsigned short* Wagg  = wb + 229376;
    unsigned short* Wout  = wb + 233472;

    dim3 blk(256);

    // 1. all conversions
    ConvArgs ca;
    ca.x = x; ca.d0 = dtw0; ca.d1 = dtw1;
    ca.wp[0] = (const float*)d_in[6];  ca.wp[1] = (const float*)d_in[7];  ca.wp[2] = (const float*)d_in[8];
    ca.wp[3] = (const float*)d_in[22]; ca.wp[4] = (const float*)d_in[23]; ca.wp[5] = (const float*)d_in[24];
    ca.wp[6] = (const float*)d_in[26]; ca.wp[7] = (const float*)d_in[27];
    ca.wp[8] = (const float*)d_in[14]; ca.wp[9] = (const float*)d_in[15]; ca.wp[10] = (const float*)d_in[16];
    ca.wp[11] = (const float*)d_in[17]; ca.wp[12] = (const float*)d_in[18]; ca.wp[13] = (const float*)d_in[19];
    ca.wp[14] = (const float*)d_in[20]; ca.wp[15] = (const float*)d_in[28];
    ca.xb = xb; ca.d0b = d0b; ca.d1b = d1b; ca.wb = wb;
    hipLaunchKernelGGL(conv_all, dim3((CTOT / 8 + 255) / 256), blk, 0, stream, ca);

    // 2. fused projection GEMM -> P bf16
    hipLaunchKernelGGL((gemm_mfma<true>), dim3(192, 8), blk, 0, stream,
                       xb, Wproj, (const float*)nullptr, (float*)nullptr, P,
                       (int)M, 512, 256, 512, 0);

    // 3. dtw projections -> bf16 (ldo 192: q|k|v)
    hipLaunchKernelGGL((gemm_mfma<true>), dim3(24, 3), blk, 0, stream,
                       d0b, Wd0, (const float*)nullptr, (float*)nullptr, qkv0b,
                       BT_ * 64, 192, 256, 192, 0);
    hipLaunchKernelGGL((gemm_mfma<true>), dim3(48, 3), blk, 0, stream,
                       d1b, Wd1, (const float*)nullptr, (float*)nullptr, qkv1b,
                       BT_ * 128, 192, 256, 192, 0);

    // 4. spatial differential attention (MFMA) -> st cols [0,64)
    hipLaunchKernelGGL(spatial_mfma, dim3(768), blk, 0, stream,
                       P, lq1, lk1, lq2, lk2, subln, st);

    // 5. agg spatial attention (MFMA, both maps) -> sgtb bf16
    hipLaunchKernelGGL(agg_mfma, dim3(768), blk, 0, stream,
                       qkv0b, qkv1b, map0, map1, sgtb);

    // 6. sgtb @ W_agg^T + b -> st cols [64,128)
    hipLaunchKernelGGL((gemm_mfma<true>), dim3(192, 1), blk, 0, stream,
                       sgtb, Wagg, b_agg, (float*)nullptr, st,
                       (int)M, 64, 64, 256, 64);

    // 7. temporal + aggregative temporal -> st cols [128,256)
    hipLaunchKernelGGL(tempta_kernel, dim3(768), blk, 0, stream, P, tq, tmpinf, st);

    // 8. output projection
    hipLaunchKernelGGL((gemm_mfma<false>), dim3(192, 4), blk, 0, stream,
                       st, Wout, (const float*)nullptr, out, (unsigned short*)nullptr,
                       (int)M, 256, 256, 256, 0);
}

// Round 5
// 128.074 us; speedup vs baseline: 6.9246x; 1.0229x over previous
//
#include <hip/hip_runtime.h>
#include <hip/hip_bf16.h>
#include <cstddef>

#define B_ 4
#define T_ 12
#define N_ 512
#define D_ 256
#define H_ 4
#define SEG_ 6
#define BT_ (B_*T_)

#define SCALE_S 0.35355339059327373f   /* 8^-0.5  */
#define SCALE_H 0.25f                  /* 16^-0.5 */
#define LOG2E   1.44269504088896340736f
#define LAMBDA_INIT 0.2f
#define EPS_ 1e-6f

typedef short bf16x8 __attribute__((ext_vector_type(8)));
typedef float f32x4 __attribute__((ext_vector_type(4)));
typedef unsigned short us8 __attribute__((ext_vector_type(8)));
typedef unsigned short us4 __attribute__((ext_vector_type(4)));

__device__ inline float b2f(unsigned short u) {
    union { unsigned int i; float f; } x; x.i = ((unsigned int)u) << 16; return x.f;
}
__device__ inline unsigned short f2bs(float f) {
    __hip_bfloat16 b = __float2bfloat16(f);
    return *(unsigned short*)&b;
}

// async global->LDS, 16 bytes per lane; ldst must be the WAVE-UNIFORM base,
// HW scatters lane i at base + i*16.
#define GLOAD16(gsrc, ldst) \
    __builtin_amdgcn_global_load_lds((const __attribute__((address_space(1))) void*)(gsrc), \
                                     (__attribute__((address_space(3))) void*)(ldst), 16, 0, 0)

// ---------------------------------------------------------------------------
// Fused fp32->bf16 conversion for all activations + weights (one launch).
// ---------------------------------------------------------------------------
struct ConvArgs {
    const float* x; const float* d0; const float* d1;
    const float* wp[16];
    unsigned short* xb; unsigned short* d0b; unsigned short* d1b; unsigned short* wb;
};
#define CSEG0 6291456
#define CSEG1 (CSEG0 + 786432)
#define CSEG2 (CSEG1 + 1572864)
#define CTOT  (CSEG2 + 299008)

__global__ __launch_bounds__(256) void conv_all(ConvArgs a)
{
    long long i = (long long)(blockIdx.x * 256 + threadIdx.x) * 8;
    if (i >= CTOT) return;
    const float* src; unsigned short* dst; long long rel;
    if (i < CSEG0)      { src = a.x;  dst = a.xb;  rel = i; }
    else if (i < CSEG1) { src = a.d0; dst = a.d0b; rel = i - CSEG0; }
    else if (i < CSEG2) { src = a.d1; dst = a.d1b; rel = i - CSEG1; }
    else {
        int widx = (int)(i - CSEG2);
#pragma unroll
        for (int k = 0; k < 8; k++) {
            int idx = widx + k;
            const float* s; int r;
            if (idx < 131072)      { s = a.wp[idx >> 14]; r = idx & 16383; }
            else if (idx < 180224) { int q = idx - 131072; s = a.wp[8 + (q >> 14)]; r = q & 16383; }
            else if (idx < 229376) { int q = idx - 180224; s = a.wp[11 + (q >> 14)]; r = q & 16383; }
            else if (idx < 233472) { s = a.wp[14]; r = idx - 229376; }
            else                   { s = a.wp[15]; r = idx - 233472; }
            a.wb[idx] = f2bs(s[r]);
        }
        return;
    }
    float4 v0 = *(const float4*)(src + rel);
    float4 v1 = *(const float4*)(src + rel + 4);
    us8 o;
    o[0] = f2bs(v0.x); o[1] = f2bs(v0.y); o[2] = f2bs(v0.z); o[3] = f2bs(v0.w);
    o[4] = f2bs(v1.x); o[5] = f2bs(v1.y); o[6] = f2bs(v1.z); o[7] = f2bs(v1.w);
    *(us8*)(dst + rel) = o;
}

// ---------------------------------------------------------------------------
// bf16 MFMA GEMM (grid: x = m-blocks of 128, y = e-blocks of 64).
// Staging via global_load_lds dwordx4 (async DMA, no VGPR round-trip).
// ---------------------------------------------------------------------------
template<bool OUT_BF16>
__global__ __launch_bounds__(256) void gemm_mfma(
    const unsigned short* __restrict__ A, const unsigned short* __restrict__ W,
    const float* __restrict__ bias, float* __restrict__ Of, unsigned short* __restrict__ Ob,
    int M, int E, int K, int ldo, int ocol)
{
    __shared__ unsigned short As[128 * 64];
    __shared__ unsigned short Ws[64 * 64];
    const int m0 = blockIdx.x * 128;
    const int e0 = blockIdx.y * 64;
    const int tid = threadIdx.x;
    const int lane = tid & 63;
    const int wid = tid >> 6;
    const int wm = wid >> 1, wn = wid & 1;
    const int l15 = lane & 15, l4 = lane >> 4;

    f32x4 acc[4][2];
#pragma unroll
    for (int i = 0; i < 4; i++)
#pragma unroll
        for (int j = 0; j < 2; j++)
#pragma unroll
            for (int r = 0; r < 4; r++) acc[i][j][r] = 0.f;

    for (int kk = 0; kk < K; kk += 64) {
#pragma unroll
        for (int p = 0; p < 4; p++) {
            int off = p * 2048 + tid * 8;           // element index in As
            int r = off >> 6, cc = off & 63;
            GLOAD16(&A[(size_t)(m0 + r) * K + kk + cc], &As[p * 2048 + wid * 512]);
        }
#pragma unroll
        for (int p = 0; p < 2; p++) {
            int off = p * 2048 + tid * 8;
            int r = off >> 6, cc = off & 63;
            GLOAD16(&W[(size_t)(e0 + r) * K + kk + cc], &Ws[p * 2048 + wid * 512]);
        }
        __syncthreads();
#pragma unroll
        for (int ks = 0; ks < 64; ks += 32) {
            bf16x8 af[4], bw[2];
#pragma unroll
            for (int i = 0; i < 4; i++)
                af[i] = *(bf16x8*)(&As[(wm * 64 + i * 16 + l15) * 64 + ks + l4 * 8]);
#pragma unroll
            for (int j = 0; j < 2; j++)
                bw[j] = *(bf16x8*)(&Ws[(wn * 32 + j * 16 + l15) * 64 + ks + l4 * 8]);
#pragma unroll
            for (int i = 0; i < 4; i++)
#pragma unroll
                for (int j = 0; j < 2; j++)
                    acc[i][j] = __builtin_amdgcn_mfma_f32_16x16x32_bf16(af[i], bw[j], acc[i][j], 0, 0, 0);
        }
        __syncthreads();
    }

#pragma unroll
    for (int i = 0; i < 4; i++)
#pragma unroll
        for (int j = 0; j < 2; j++) {
            int row0 = m0 + wm * 64 + i * 16 + l4 * 4;
            int col = ocol + e0 + wn * 32 + j * 16 + l15;
            float bv = bias ? bias[e0 + wn * 32 + j * 16 + l15] : 0.f;
#pragma unroll
            for (int r = 0; r < 4; r++) {
                float v = acc[i][j][r] + bv;
                if (OUT_BF16) Ob[(size_t)(row0 + r) * ldo + col] = f2bs(v);
                else          Of[(size_t)(row0 + r) * ldo + col] = v;
            }
        }
}

// ---------------------------------------------------------------------------
// Spatial differential attention (MFMA) — unchanged.
// ---------------------------------------------------------------------------
__global__ __launch_bounds__(256) void spatial_mfma(
    const unsigned short* __restrict__ P,
    const float* __restrict__ lq1, const float* __restrict__ lk1,
    const float* __restrict__ lq2, const float* __restrict__ lk2,
    const float* __restrict__ subln, unsigned short* __restrict__ st)
{
    __shared__ unsigned short Kl[512][24];
    __shared__ unsigned short Vt[16][520];
    __shared__ unsigned short Pl[4][32][40];

    const int bid = blockIdx.x;
    const int bth = bid >> 2, qc = bid & 3;
    const int h = bth & 3, bt = bth >> 2;
    const int tid = threadIdx.x;

    const unsigned short* kbase = P + (size_t)bt * N_ * 512 + 64 + h * 16;
    const unsigned short* vbase = P + (size_t)bt * N_ * 512 + 128 + h * 16;
    const float kscale = SCALE_S * LOG2E;
    for (int i = tid; i < 512; i += 256) {
        us8 k0 = *(const us8*)(kbase + (size_t)i * 512);
        us8 k1 = *(const us8*)(kbase + (size_t)i * 512 + 8);
        us8 s0, s1;
#pragma unroll
        for (int r = 0; r < 8; r++) {
            s0[r] = f2bs(b2f(k0[r]) * kscale);
            s1[r] = f2bs(b2f(k1[r]) * kscale);
        }
        *(us8*)&Kl[i][0] = s0;
        *(us8*)&Kl[i][8] = s1;
        us8 v0 = *(const us8*)(vbase + (size_t)i * 512);
        us8 v1 = *(const us8*)(vbase + (size_t)i * 512 + 8);
#pragma unroll
        for (int e = 0; e < 8; e++) { Vt[e][i] = v0[e]; Vt[8 + e][i] = v1[e]; }
    }
    __syncthreads();

    float e1 = 0.f, e2 = 0.f;
#pragma unroll
    for (int j = 0; j < 8; j++) { e1 += lq1[j] * lk1[j]; e2 += lq2[j] * lk2[j]; }
    const float lam = __expf(e1) - __expf(e2) + LAMBDA_INIT;

    const int lane = tid & 63, w = tid >> 6;
    const int l15 = lane & 15, g = lane >> 4;
    const int q0 = qc * 128 + w * 32;

    bf16x8 qf[2];
#pragma unroll
    for (int qt = 0; qt < 2; qt++)
        qf[qt] = *(const bf16x8*)(P + ((size_t)bt * N_ + q0 + qt * 16 + l15) * 512 + h * 16 + (g & 1) * 8);

    const f32x4 z4 = {0.f, 0.f, 0.f, 0.f};
    const bf16x8 zb = {0, 0, 0, 0, 0, 0, 0, 0};
    f32x4 O1[2], O2[2];
#pragma unroll
    for (int qt = 0; qt < 2; qt++)
#pragma unroll
        for (int r = 0; r < 4; r++) { O1[qt][r] = 0.f; O2[qt][r] = 0.f; }
    float rs1[2] = {0.f, 0.f}, rs2[2] = {0.f, 0.f};

    for (int mc = 0; mc < 512; mc += 32) {
        bf16x8 kva = *(bf16x8*)&Kl[mc + l15][(g & 1) * 8];
        bf16x8 kvb = *(bf16x8*)&Kl[mc + 16 + l15][(g & 1) * 8];
        bf16x8 a1a = (g == 0) ? kva : zb, a2a = (g == 1) ? kva : zb;
        bf16x8 a1b = (g == 0) ? kvb : zb, a2b = (g == 1) ? kvb : zb;
        bf16x8 vf = *(bf16x8*)&Vt[l15][mc + g * 8];

        f32x4 s1a[2], s1b[2], s2a[2], s2b[2];
#pragma unroll
        for (int qt = 0; qt < 2; qt++) {
            s1a[qt] = __builtin_amdgcn_mfma_f32_16x16x32_bf16(a1a, qf[qt], z4, 0, 0, 0);
            s1b[qt] = __builtin_amdgcn_mfma_f32_16x16x32_bf16(a1b, qf[qt], z4, 0, 0, 0);
            s2a[qt] = __builtin_amdgcn_mfma_f32_16x16x32_bf16(a2a, qf[qt], z4, 0, 0, 0);
            s2b[qt] = __builtin_amdgcn_mfma_f32_16x16x32_bf16(a2b, qf[qt], z4, 0, 0, 0);
        }

#pragma unroll
        for (int qt = 0; qt < 2; qt++) {
            f32x4 p0, p1;
#pragma unroll
            for (int r = 0; r < 4; r++) {
                p0[r] = __builtin_amdgcn_exp2f(s1a[qt][r]);
                p1[r] = __builtin_amdgcn_exp2f(s1b[qt][r]);
            }
            rs1[qt] += p0[0] + p0[1] + p0[2] + p0[3] + p1[0] + p1[1] + p1[2] + p1[3];
            us4 w0, w1;
#pragma unroll
            for (int r = 0; r < 4; r++) { w0[r] = f2bs(p0[r]); w1[r] = f2bs(p1[r]); }
            *(us4*)&Pl[w][qt * 16 + l15][g * 4] = w0;
            *(us4*)&Pl[w][qt * 16 + l15][16 + g * 4] = w1;
        }
#pragma unroll
        for (int qt = 0; qt < 2; qt++) {
            bf16x8 pf = *(bf16x8*)&Pl[w][qt * 16 + l15][g * 8];
            O1[qt] = __builtin_amdgcn_mfma_f32_16x16x32_bf16(pf, vf, O1[qt], 0, 0, 0);
        }
#pragma unroll
        for (int qt = 0; qt < 2; qt++) {
            f32x4 p0, p1;
#pragma unroll
            for (int r = 0; r < 4; r++) {
                p0[r] = __builtin_amdgcn_exp2f(s2a[qt][r]);
                p1[r] = __builtin_amdgcn_exp2f(s2b[qt][r]);
            }
            rs2[qt] += p0[0] + p0[1] + p0[2] + p0[3] + p1[0] + p1[1] + p1[2] + p1[3];
            us4 w0, w1;
#pragma unroll
            for (int r = 0; r < 4; r++) { w0[r] = f2bs(p0[r]); w1[r] = f2bs(p1[r]); }
            *(us4*)&Pl[w][qt * 16 + l15][g * 4] = w0;
            *(us4*)&Pl[w][qt * 16 + l15][16 + g * 4] = w1;
        }
#pragma unroll
        for (int qt = 0; qt < 2; qt++) {
            bf16x8 pf = *(bf16x8*)&Pl[w][qt * 16 + l15][g * 8];
            O2[qt] = __builtin_amdgcn_mfma_f32_16x16x32_bf16(pf, vf, O2[qt], 0, 0, 0);
        }
    }

#pragma unroll
    for (int qt = 0; qt < 2; qt++) {
        rs1[qt] += __shfl_xor(rs1[qt], 16); rs1[qt] += __shfl_xor(rs1[qt], 32);
        rs2[qt] += __shfl_xor(rs2[qt], 16); rs2[qt] += __shfl_xor(rs2[qt], 32);
    }

    const float sw = subln[l15];
#pragma unroll
    for (int qt = 0; qt < 2; qt++) {
#pragma unroll
        for (int r = 0; r < 4; r++) {
            int qrow = g * 4 + r;
            float s1 = __shfl(rs1[qt], qrow);
            float s2 = __shfl(rs2[qt], qrow);
            float o = O1[qt][r] / s1 - lam * (O2[qt][r] / s2);
            float ss = o * o;
            ss += __shfl_xor(ss, 1); ss += __shfl_xor(ss, 2);
            ss += __shfl_xor(ss, 4); ss += __shfl_xor(ss, 8);
            float rms = rsqrtf(ss * (1.0f / 16.0f) + EPS_);
            float val = 0.8f * o * rms * sw;
            int q = q0 + qt * 16 + qrow;
            st[((size_t)bt * N_ + q) * 256 + h * 16 + l15] = f2bs(val);
        }
    }
}

// ---------------------------------------------------------------------------
// DTW-aggregated spatial attention (MFMA), both maps fused — unchanged.
// ---------------------------------------------------------------------------
template<int C>
__device__ inline void agg_phase(
    const unsigned short* __restrict__ qkv, const float* __restrict__ cmap,
    unsigned short* SH, int bt, int h, int nq,
    int tid, int w, int l15, int g, float oacc[2][4])
{
    unsigned short* T  = SH;            // [128][136]
    unsigned short* Kf = SH + 17408;    // [128][40]
    unsigned short* Vt = SH + 22528;    // [16][136]
    unsigned short* QT = SH + 24704;    // [16][136]
    unsigned short* Qb = SH + 26880;    // [128][40]

    for (int i = tid; i < C * 128; i += 256) {
        int c = i >> 7, nn = i & 127;
        T[nn * 136 + c] = f2bs(cmap[(size_t)c * 512 + nq * 128 + nn]);
    }
    const us8 z8 = {0, 0, 0, 0, 0, 0, 0, 0};
    for (int i = tid; i < C * 2; i += 256) {
        int c = i >> 1, hf = i & 1;
        const unsigned short* base = qkv + ((size_t)(bt * C + c)) * 192 + h * 16 + hf * 8;
        us8 qv = *(const us8*)(base);
        us8 kv = *(const us8*)(base + 64);
        us8 vv = *(const us8*)(base + 128);
        *(us8*)&Kf[c * 40 + hf * 8] = kv;
        *(us8*)&Kf[c * 40 + 16 + hf * 8] = z8;
#pragma unroll
        for (int e = 0; e < 8; e++) {
            QT[(hf * 8 + e) * 136 + c] = qv[e];
            Vt[(hf * 8 + e) * 136 + c] = vv[e];
        }
    }
    __syncthreads();

    const f32x4 z4 = {0.f, 0.f, 0.f, 0.f};
    f32x4 qac[2] = {z4, z4};
    for (int kk = 0; kk < C; kk += 32) {
        bf16x8 bwq = *(bf16x8*)&QT[l15 * 136 + kk + g * 8];
#pragma unroll
        for (int qt = 0; qt < 2; qt++) {
            bf16x8 af = *(bf16x8*)&T[(w * 32 + qt * 16 + l15) * 136 + kk + g * 8];
            qac[qt] = __builtin_amdgcn_mfma_f32_16x16x32_bf16(af, bwq, qac[qt], 0, 0, 0);
        }
    }
    const float qs = SCALE_H * LOG2E;
#pragma unroll
    for (int qt = 0; qt < 2; qt++)
#pragma unroll
        for (int r = 0; r < 4; r++) {
            int row = w * 32 + qt * 16 + g * 4 + r;
            Qb[row * 40 + l15] = f2bs(qac[qt][r] * qs);
            Qb[row * 40 + 16 + l15] = 0;
        }
    __syncthreads();

    unsigned short* Pl = SH;
    f32x4 O[2] = {z4, z4};
    float rs[2] = {0.f, 0.f};

    for (int mc = 0; mc < C; mc += 32) {
        bf16x8 kva = *(bf16x8*)&Kf[(mc + l15) * 40 + g * 8];
        bf16x8 kvb = *(bf16x8*)&Kf[(mc + 16 + l15) * 40 + g * 8];
        bf16x8 vf  = *(bf16x8*)&Vt[l15 * 136 + mc + g * 8];
#pragma unroll
        for (int qt = 0; qt < 2; qt++) {
            bf16x8 qf2 = *(bf16x8*)&Qb[(w * 32 + qt * 16 + l15) * 40 + g * 8];
            f32x4 sa = __builtin_amdgcn_mfma_f32_16x16x32_bf16(kva, qf2, z4, 0, 0, 0);
            f32x4 sb = __builtin_amdgcn_mfma_f32_16x16x32_bf16(kvb, qf2, z4, 0, 0, 0);
            f32x4 pa, pb;
#pragma unroll
            for (int r = 0; r < 4; r++) {
                pa[r] = __builtin_amdgcn_exp2f(sa[r]);
                pb[r] = __builtin_amdgcn_exp2f(sb[r]);
            }
            rs[qt] += pa[0] + pa[1] + pa[2] + pa[3] + pb[0] + pb[1] + pb[2] + pb[3];
            us4 wa, wb2;
#pragma unroll
            for (int r = 0; r < 4; r++) { wa[r] = f2bs(pa[r]); wb2[r] = f2bs(pb[r]); }
            *(us4*)&Pl[(w * 32 + qt * 16 + l15) * 40 + g * 4] = wa;
            *(us4*)&Pl[(w * 32 + qt * 16 + l15) * 40 + 16 + g * 4] = wb2;
        }
#pragma unroll
        for (int qt = 0; qt < 2; qt++) {
            bf16x8 pf = *(bf16x8*)&Pl[(w * 32 + qt * 16 + l15) * 40 + g * 8];
            O[qt] = __builtin_amdgcn_mfma_f32_16x16x32_bf16(pf, vf, O[qt], 0, 0, 0);
        }
    }

#pragma unroll
    for (int qt = 0; qt < 2; qt++) {
        rs[qt] += __shfl_xor(rs[qt], 16);
        rs[qt] += __shfl_xor(rs[qt], 32);
    }
#pragma unroll
    for (int qt = 0; qt < 2; qt++)
#pragma unroll
        for (int r = 0; r < 4; r++) {
            float sum = __shfl(rs[qt], g * 4 + r);
            oacc[qt][r] += O[qt][r] / sum;
        }
    __syncthreads();
}

__global__ __launch_bounds__(256) void agg_mfma(
    const unsigned short* __restrict__ qkv0, const unsigned short* __restrict__ qkv1,
    const float* __restrict__ map0, const float* __restrict__ map1,
    unsigned short* __restrict__ sgtb)
{
    __shared__ unsigned short SH[32000];
    const int bid = blockIdx.x;
    const int bth = bid >> 2, nq = bid & 3;
    const int h = bth & 3, bt = bth >> 2;
    const int tid = threadIdx.x;
    const int lane = tid & 63, w = tid >> 6;
    const int l15 = lane & 15, g = lane >> 4;

    float oacc[2][4] = {};
    agg_phase<64>(qkv0, map0, SH, bt, h, nq, tid, w, l15, g, oacc);
    agg_phase<128>(qkv1, map1, SH, bt, h, nq, tid, w, l15, g, oacc);

#pragma unroll
    for (int qt = 0; qt < 2; qt++)
#pragma unroll
        for (int r = 0; r < 4; r++) {
            int n = nq * 128 + w * 32 + qt * 16 + g * 4 + r;
            sgtb[((size_t)(bt * N_ + n)) * 64 + h * 16 + l15] = f2bs(oacc[qt][r]);
        }
}

// ---------------------------------------------------------------------------
// Temporal + aggregative temporal attention v2: one block per (b,n).
// Stages P[b, 0..11, n, 192..512) in LDS (coalesced), then 96 threads
// each compute one (part, h, t) item entirely from LDS.
// LDS cols (relative): qt@0, kt@64, vt@128, kta@192, vta@256.
// ---------------------------------------------------------------------------
__global__ __launch_bounds__(128) void tempta_v2(
    const unsigned short* __restrict__ P,
    const float* __restrict__ tq, const float* __restrict__ ti,
    unsigned short* __restrict__ st)
{
    const int b = blockIdx.x >> 9;
    const int n = blockIdx.x & 511;
    __shared__ unsigned short Pt[T_][328];

    for (int i = threadIdx.x; i < T_ * 40; i += 128) {
        int u = i / 40, c8 = i % 40;
        *(us8*)&Pt[u][c8 * 8] = *(const us8*)(P + (((size_t)(b * T_ + u) * N_) + n) * 512 + 192 + c8 * 8);
    }
    __syncthreads();

    const int i = threadIdx.x;
    if (i >= 96) return;
    const int part = i / 48;
    const int rem = i % 48;
    const int h = rem / T_, t = rem % T_;

    float q[16];
    if (!part) {
        us8 a = *(const us8*)&Pt[t][h * 16];
        us8 bq = *(const us8*)&Pt[t][h * 16 + 8];
#pragma unroll
        for (int f = 0; f < 8; f++) { q[f] = b2f(a[f]); q[8 + f] = b2f(bq[f]); }
    } else {
        float wseg[SEG_];
#pragma unroll
        for (int s = 0; s < SEG_; s++)
            wseg[s] = ti[(((size_t)b * N_ + n) * T_ + t) * SEG_ + s];
#pragma unroll
        for (int f = 0; f < 16; f++) q[f] = 0.f;
        for (int s = 0; s < SEG_; s++) {
            const float* qa = tq + ((size_t)n * SEG_ + s) * 64 + h * 16;
#pragma unroll
            for (int f = 0; f < 16; f++) q[f] += wseg[s] * qa[f];
        }
    }
    const int kc = part ? 192 : 64;
    const int vc = part ? 256 : 128;

    float sc[T_]; float mx = -1e30f;
    for (int u = 0; u < T_; u++) {
        us8 a = *(const us8*)&Pt[u][kc + h * 16];
        us8 bk = *(const us8*)&Pt[u][kc + h * 16 + 8];
        float s = 0.f;
#pragma unroll
        for (int f = 0; f < 8; f++) s += q[f] * b2f(a[f]) + q[8 + f] * b2f(bk[f]);
        s *= SCALE_H;
        sc[u] = s; mx = fmaxf(mx, s);
    }
    float sum = 0.f;
    for (int u = 0; u < T_; u++) { sc[u] = __expf(sc[u] - mx); sum += sc[u]; }
    float inv = 1.0f / sum;
    float o[16] = {};
    for (int u = 0; u < T_; u++) {
        us8 a = *(const us8*)&Pt[u][vc + h * 16];
        us8 bv = *(const us8*)&Pt[u][vc + h * 16 + 8];
        float ww = sc[u] * inv;
#pragma unroll
        for (int f = 0; f < 8; f++) { o[f] += ww * b2f(a[f]); o[8 + f] += ww * b2f(bv[f]); }
    }
    unsigned short* orow = st + (((size_t)(b * T_ + t) * N_) + n) * 256 + (part ? 192 : 128) + h * 16;
    us8 w0, w1;
#pragma unroll
    for (int f = 0; f < 8; f++) { w0[f] = f2bs(o[f]); w1[f] = f2bs(o[8 + f]); }
    *(us8*)orow = w0;
    *(us8*)(orow + 8) = w1;
}

// ---------------------------------------------------------------------------
extern "C" void kernel_launch(void* const* d_in, const int* in_sizes, int n_in,
                              void* d_out, int out_size, void* d_ws, size_t ws_size,
                              hipStream_t stream)
{
    const float* x      = (const float*)d_in[0];
    const float* dtw0   = (const float*)d_in[1];
    const float* dtw1   = (const float*)d_in[2];
    const float* map0   = (const float*)d_in[3];
    const float* map1   = (const float*)d_in[4];
    const float* tmpinf = (const float*)d_in[5];
    const float* lq1    = (const float*)d_in[9];
    const float* lk1    = (const float*)d_in[10];
    const float* lq2    = (const float*)d_in[11];
    const float* lk2    = (const float*)d_in[12];
    const float* subln  = (const float*)d_in[13];
    const float* b_agg  = (const float*)d_in[21];
    const float* tq     = (const float*)d_in[25];
    float* out = (float*)d_out;

    const size_t M = (size_t)BT_ * N_;   // 24576

    char* w = (char*)d_ws;
    unsigned short* P     = (unsigned short*)w;   w += M * 512 * 2;
    unsigned short* st    = (unsigned short*)w;   w += M * 256 * 2;
    unsigned short* qkv0b = (unsigned short*)w;   w += (size_t)BT_ * 64 * 192 * 2;
    unsigned short* qkv1b = (unsigned short*)w;   w += (size_t)BT_ * 128 * 192 * 2;
    unsigned short* xb    = (unsigned short*)w;   w += M * 256 * 2;
    unsigned short* d0b   = (unsigned short*)w;   w += (size_t)BT_ * 64 * 256 * 2;
    unsigned short* d1b   = (unsigned short*)w;   w += (size_t)BT_ * 128 * 256 * 2;
    unsigned short* sgtb  = (unsigned short*)w;   w += M * 64 * 2;
    unsigned short* wb    = (unsigned short*)w;   w += 299008 * 2;

    unsigned short* Wproj = wb;
    unsigned short* Wd0   = wb + 131072;
    unsigned short* Wd1   = wb + 180224;
    unsigned short* Wagg  = wb + 229376;
    unsigned short* Wout  = wb + 233472;

    dim3 blk(256);

    // 1. all conversions
    ConvArgs ca;
    ca.x = x; ca.d0 = dtw0; ca.d1 = dtw1;
    ca.wp[0] = (const float*)d_in[6];  ca.wp[1] = (const float*)d_in[7];  ca.wp[2] = (const float*)d_in[8];
    ca.wp[3] = (const float*)d_in[22]; ca.wp[4] = (const float*)d_in[23]; ca.wp[5] = (const float*)d_in[24];
    ca.wp[6] = (const float*)d_in[26]; ca.wp[7] = (const float*)d_in[27];
    ca.wp[8] = (const float*)d_in[14]; ca.wp[9] = (const float*)d_in[15]; ca.wp[10] = (const float*)d_in[16];
    ca.wp[11] = (const float*)d_in[17]; ca.wp[12] = (const float*)d_in[18]; ca.wp[13] = (const float*)d_in[19];
    ca.wp[14] = (const float*)d_in[20]; ca.wp[15] = (const float*)d_in[28];
    ca.xb = xb; ca.d0b = d0b; ca.d1b = d1b; ca.wb = wb;
    hipLaunchKernelGGL(conv_all, dim3((CTOT / 8 + 255) / 256), blk, 0, stream, ca);

    // 2. fused projection GEMM -> P bf16
    hipLaunchKernelGGL((gemm_mfma<true>), dim3(192, 8), blk, 0, stream,
                       xb, Wproj, (const float*)nullptr, (float*)nullptr, P,
                       (int)M, 512, 256, 512, 0);

    // 3. dtw projections -> bf16 (ldo 192: q|k|v)
    hipLaunchKernelGGL((gemm_mfma<true>), dim3(24, 3), blk, 0, stream,
                       d0b, Wd0, (const float*)nullptr, (float*)nullptr, qkv0b,
                       BT_ * 64, 192, 256, 192, 0);
    hipLaunchKernelGGL((gemm_mfma<true>), dim3(48, 3), blk, 0, stream,
                       d1b, Wd1, (const float*)nullptr, (float*)nullptr, qkv1b,
                       BT_ * 128, 192, 256, 192, 0);

    // 4. spatial differential attention (MFMA) -> st cols [0,64)
    hipLaunchKernelGGL(spatial_mfma, dim3(768), blk, 0, stream,
                       P, lq1, lk1, lq2, lk2, subln, st);

    // 5. agg spatial attention (MFMA, both maps) -> sgtb bf16
    hipLaunchKernelGGL(agg_mfma, dim3(768), blk, 0, stream,
                       qkv0b, qkv1b, map0, map1, sgtb);

    // 6. sgtb @ W_agg^T + b -> st cols [64,128)
    hipLaunchKernelGGL((gemm_mfma<true>), dim3(192, 1), blk, 0, stream,
                       sgtb, Wagg, b_agg, (float*)nullptr, st,
                       (int)M, 64, 64, 256, 64);

    // 7. temporal + aggregative temporal -> st cols [128,256)
    hipLaunchKernelGGL(tempta_v2, dim3(B_ * N_), dim3(128), 0, stream, P, tq, tmpinf, st);

    // 8. output projection
    hipLaunchKernelGGL((gemm_mfma<false>), dim3(192, 4), blk, 0, stream,
                       st, Wout, (const float*)nullptr, out, (unsigned short*)nullptr,
                       (int)M, 256, 256, 256, 0);
}